// Round 2
// baseline (1583.549 us; speedup 1.0000x reference)
//
#include <hip/hip_runtime.h>
#include <math.h>

#define NB 2
#define NN1 4096
#define NN2 8192
#define NPART 8
#define LEAKK 0.1f

__device__ __forceinline__ float leaky_(float x) { return fmaxf(x, LEAKK * x); }
__device__ __forceinline__ float sigm_(float x) { return 1.0f / (1.0f + __expf(-x)); }

// merge two sorted 8-lists, keep first 8 (result in a)
__device__ __forceinline__ void merge8_(float* ad, int* ai, float* bd, int* bi) {
  float rd[8]; int ri[8];
#pragma unroll
  for (int s = 0; s < 8; ++s) {
    bool ta = (ad[0] < bd[0]) || (ad[0] == bd[0] && ai[0] < bi[0]);
    rd[s] = ta ? ad[0] : bd[0];
    ri[s] = ta ? ai[0] : bi[0];
#pragma unroll
    for (int j = 0; j < 7; ++j) {
      ad[j] = ta ? ad[j + 1] : ad[j];
      ai[j] = ta ? ai[j + 1] : ai[j];
      bd[j] = ta ? bd[j] : bd[j + 1];
      bi[j] = ta ? bi[j] : bi[j + 1];
    }
  }
#pragma unroll
  for (int j = 0; j < 8; ++j) { ad[j] = rd[j]; ai[j] = ri[j]; }
}

// wave-ballot top-8 scan: each of 64 lanes holds one candidate (d, idx0+lane).
// Sorted ascending lex (d,i) list of 8 lives in LDS at Ld/Li[base8..base8+8).
// All 64 lanes of the wave must be active (row-uniform base8).
__device__ __forceinline__ void scan_half_(float d, int idx0, int base8,
                                           float* Ld, int* Li, int lane) {
  float l7 = Ld[base8 + 7];
  int   i7 = Li[base8 + 7];
  int myi = idx0 + lane;
  unsigned long long m = __ballot((d < l7) | ((d == l7) & (myi < i7)));
  if (m == 0ULL) return;
  int j = lane & 7;
  while (m) {
    int s = __ffsll(m) - 1;
    m &= m - 1;
    float ds = __shfl(d, s);
    int   is = idx0 + s;
    // exact re-check against current 8th
    if ((ds < l7) | ((ds == l7) & (is < i7))) {
      float lj = Ld[base8 + j];
      int   ij = Li[base8 + j];
      bool less = (lj < ds) | ((lj == ds) & (ij < is));
      int p = (int)__popcll(__ballot(less) & 0xFFULL);
      int jm1 = (j > 0) ? (j - 1) : 0;
      float sd = Ld[base8 + jm1];
      int   si = Li[base8 + jm1];
      float nd = (j == p) ? ds : ((j > p) ? sd : lj);
      int   ni = (j == p) ? is : ((j > p) ? si : ij);
      if (lane < 8) { Ld[base8 + lane] = nd; Li[base8 + lane] = ni; }
      l7 = __shfl(nd, 7);
      i7 = __shfl(ni, 7);
      // prune survivors with updated threshold (exact)
      m &= __ballot((d < l7) | ((d == l7) & (myi < i7)));
    }
  }
}

// ---------------- K0: transpose all 15 weight matrices into ws ----------------
__global__ void prep_w_kernel(const float* s0, const float* s1, const float* s2,
                              const float* s3, const float* s4, const float* s5,
                              const float* s6, const float* s7, const float* s8,
                              const float* s9, const float* s10, const float* s11,
                              const float* s12, const float* s13, const float* s14,
                              float* wt) {
  const float* srcs[15] = {s0, s1, s2, s3, s4, s5, s6, s7, s8, s9, s10, s11, s12, s13, s14};
  int bid = blockIdx.x;
  const float* src = srcs[bid];
  int cols = (bid < 6) ? 64 : (((bid - 6) % 3 == 0) ? 3 : 64);
  float* dst = wt + bid * 4096;
  for (int e = threadIdx.x; e < 64 * cols; e += blockDim.x) {
    int o = e / cols, c = e - o * cols;
    dst[c * 64 + o] = src[e];
  }
}

// ---------------- K1: transpose+normalize knn features, pack xyz+|x|^2 ----------------
__global__ __launch_bounds__(64) void prep_side_kernel(const float* knn, const float* xyz,
                                                       float* fdst, float* xdst, int N) {
  __shared__ float T[64 * 65];
  __shared__ float rs[64];
  int b = blockIdx.y;
  int n0 = blockIdx.x * 64;
  int l = threadIdx.x;
  const float* kb = knn + (size_t)b * 64 * N + n0;
  for (int c = 0; c < 64; ++c) T[c * 65 + l] = kb[(size_t)c * N + l];
  __syncthreads();
  float s = 0.f;
  for (int c = 0; c < 64; ++c) { float v = T[c * 65 + l]; s += v * v; }
  rs[l] = 1.0f / sqrtf(s + 1e-8f);
  __syncthreads();
  for (int i = 0; i < 64; ++i)
    fdst[(size_t)(b * N + n0 + i) * 64 + l] = T[l * 65 + i] * rs[i];
  const float* xb = xyz + (size_t)b * 3 * N + n0;
  float x = xb[l], y = xb[N + l], z = xb[2 * N + l];
  ((float4*)xdst)[b * N + n0 + l] = make_float4(x, y, z, x * x + y * y + z * z);
}

// ---------------- K2: three fused 1x1 conv matvecs ----------------
__global__ __launch_bounds__(256) void fuse_kernel(const float* pts, const float* wt0,
                                                   const float* wt1, const float* wt2,
                                                   float* d0, float* d1, float* d2, int N) {
  int b = blockIdx.y;
  int w = threadIdx.x >> 6, l = threadIdx.x & 63;
  int n = blockIdx.x * 4 + w;
  const float* pb = pts + (size_t)b * 64 * N + n;
  float a0 = 0.f, a1 = 0.f, a2 = 0.f;
  for (int c = 0; c < 64; ++c) {
    float p = pb[(size_t)c * N];
    a0 += p * wt0[c * 64 + l];
    a1 += p * wt1[c * 64 + l];
    a2 += p * wt2[c * 64 + l];
  }
  size_t ob = (size_t)(b * N + n) * 64 + l;
  d0[ob] = a0; d1[ob] = a1; d2[ob] = a2;
}

// ---------------- K3: dual-metric partitioned KNN (v2: ballot-scan top-k) ----------------
// block: 256 threads, rows n0..n0+64, candidate partition of 1024 cols in 8 chunks of 128.
// LDS: f1t 16KB, f2t 32KB (reused as cos-distance tile), x1s 1KB, x2s 2KB, lists 8KB = 59KB.
__global__ __launch_bounds__(256) void knn_kernel(const float* f1n, const float* f2n,
                                                  const float* x1t, const float* x2t,
                                                  float* pd, int* pi) {
  __shared__ float f1t[64 * 64];     // [k][row]
  __shared__ float f2t[64 * 128];    // [k][cand]  -> reused as dtile[row][128]
  __shared__ float x1s[64 * 4];
  __shared__ float x2s[128 * 4];
  __shared__ float Ld[64 * 2 * 8];   // [row][metric][8]
  __shared__ int   Li[64 * 2 * 8];

  int t = threadIdx.x;
  int lane = t & 63, w = t >> 6;
  int n0 = blockIdx.x * 64;
  int part = (int)blockIdx.y;
  int b = (int)blockIdx.z;

  // stage f1 tile (k-major) + x1
  {
    const float* f1row = f1n + (size_t)(b * NN1 + n0 + lane) * 64;
#pragma unroll
    for (int pass = 0; pass < 4; ++pass) {
      int c0 = pass * 16 + w * 4;
      float4 v = *(const float4*)(f1row + c0);
      f1t[(c0 + 0) * 64 + lane] = v.x;
      f1t[(c0 + 1) * 64 + lane] = v.y;
      f1t[(c0 + 2) * 64 + lane] = v.z;
      f1t[(c0 + 3) * 64 + lane] = v.w;
    }
    if (t < 64) ((float4*)x1s)[t] = ((const float4*)x1t)[b * NN1 + n0 + t];
  }
  for (int j = t; j < 64 * 2 * 8; j += 256) { Ld[j] = INFINITY; Li[j] = 0x7fffffff; }
  __syncthreads();

  int ty = t >> 4, tx = t & 15;   // matmul mapping: rows ty*4.., cols {tx*4.., 64+tx*4..}

  for (int ch = 0; ch < 8; ++ch) {
    int cc = part * 1024 + ch * 128;

    // stage f2 chunk (k-major) + x2
    {
      int cand = t & 127;
      int sb = (t >> 7) * 8;   // 8 float4 feature-slots per thread
      const float* src = f2n + (size_t)(b * NN2 + cc + cand) * 64 + sb * 4;
#pragma unroll
      for (int p = 0; p < 8; ++p) {
        float4 v = *(const float4*)(src + p * 4);
        int c0 = (sb + p) * 4;
        f2t[(c0 + 0) * 128 + cand] = v.x;
        f2t[(c0 + 1) * 128 + cand] = v.y;
        f2t[(c0 + 2) * 128 + cand] = v.z;
        f2t[(c0 + 3) * 128 + cand] = v.w;
      }
      if (t < 128) ((float4*)x2s)[t] = ((const float4*)x2t)[b * NN2 + cc + t];
    }
    __syncthreads();

    // 64x128 cos-similarity tile, 4 rows x 8 cols per thread (split-column)
    float acc0[4][4], acc1[4][4];
#pragma unroll
    for (int i = 0; i < 4; ++i)
#pragma unroll
      for (int j = 0; j < 4; ++j) { acc0[i][j] = 0.f; acc1[i][j] = 0.f; }

#pragma unroll 4
    for (int k = 0; k < 64; ++k) {
      float4 a  = *(const float4*)&f1t[k * 64 + ty * 4];
      float4 b0 = *(const float4*)&f2t[k * 128 + tx * 4];
      float4 b1 = *(const float4*)&f2t[k * 128 + 64 + tx * 4];
      acc0[0][0] += a.x * b0.x; acc0[0][1] += a.x * b0.y; acc0[0][2] += a.x * b0.z; acc0[0][3] += a.x * b0.w;
      acc0[1][0] += a.y * b0.x; acc0[1][1] += a.y * b0.y; acc0[1][2] += a.y * b0.z; acc0[1][3] += a.y * b0.w;
      acc0[2][0] += a.z * b0.x; acc0[2][1] += a.z * b0.y; acc0[2][2] += a.z * b0.z; acc0[2][3] += a.z * b0.w;
      acc0[3][0] += a.w * b0.x; acc0[3][1] += a.w * b0.y; acc0[3][2] += a.w * b0.z; acc0[3][3] += a.w * b0.w;
      acc1[0][0] += a.x * b1.x; acc1[0][1] += a.x * b1.y; acc1[0][2] += a.x * b1.z; acc1[0][3] += a.x * b1.w;
      acc1[1][0] += a.y * b1.x; acc1[1][1] += a.y * b1.y; acc1[1][2] += a.y * b1.z; acc1[1][3] += a.y * b1.w;
      acc1[2][0] += a.z * b1.x; acc1[2][1] += a.z * b1.y; acc1[2][2] += a.z * b1.z; acc1[2][3] += a.z * b1.w;
      acc1[3][0] += a.w * b1.x; acc1[3][1] += a.w * b1.y; acc1[3][2] += a.w * b1.z; acc1[3][3] += a.w * b1.w;
    }
    __syncthreads();   // all waves done reading f2t

    // write cos distances (1 - dot) into the f2t space as dtile[row][128]
#pragma unroll
    for (int i = 0; i < 4; ++i) {
      *(float4*)&f2t[(ty * 4 + i) * 128 + tx * 4] =
          make_float4(1.f - acc0[i][0], 1.f - acc0[i][1], 1.f - acc0[i][2], 1.f - acc0[i][3]);
      *(float4*)&f2t[(ty * 4 + i) * 128 + 64 + tx * 4] =
          make_float4(1.f - acc1[i][0], 1.f - acc1[i][1], 1.f - acc1[i][2], 1.f - acc1[i][3]);
    }
    __syncthreads();

    // selection scan: wave w handles rows [w*16, w*16+16)
    float4 xa2 = ((float4*)x2s)[lane];
    float4 xb2 = ((float4*)x2s)[64 + lane];
    for (int r = w * 16; r < w * 16 + 16; ++r) {
      // cosine (metric 0) from dtile
      {
        int base8 = r * 16;
        float da = f2t[r * 128 + lane];
        float db = f2t[r * 128 + 64 + lane];
        scan_half_(da, cc, base8, Ld, Li, lane);
        scan_half_(db, cc + 64, base8, Ld, Li, lane);
      }
      // euclidean (metric 1) computed on the fly
      {
        int base8 = r * 16 + 8;
        float4 x1v = ((float4*)x1s)[r];
        float da = x1v.w + xa2.w - 2.f * (x1v.x * xa2.x + x1v.y * xa2.y + x1v.z * xa2.z);
        float db = x1v.w + xb2.w - 2.f * (x1v.x * xb2.x + x1v.y * xb2.y + x1v.z * xb2.z);
        scan_half_(da, cc, base8, Ld, Li, lane);
        scan_half_(db, cc + 64, base8, Ld, Li, lane);
      }
    }
    __syncthreads();   // before next chunk overwrites f2t / x2s
  }

  // write out sorted lists (metric 0 = cosine first, matching [idx_c, idx_p])
  if (t < 128) {
    int typ = t >> 6, r = t & 63;
    int base8 = (r * 2 + typ) * 8;
    size_t base = ((size_t)(b * NPART + part) * NN1 + n0 + r) * 16 + typ * 8;
#pragma unroll
    for (int j = 0; j < 8; ++j) { pd[base + j] = Ld[base8 + j]; pi[base + j] = Li[base8 + j]; }
  }
}

// ---------------- K4: merge the NPART partial lists -> final idx ----------------
__device__ __forceinline__ void loadlist_(const float* pd, const int* pi, int b, int p, int n1,
                                          int typ, float* d, int* i) {
  size_t base = ((size_t)(b * NPART + p) * NN1 + n1) * 16 + typ * 8;
#pragma unroll
  for (int j = 0; j < 8; ++j) { d[j] = pd[base + j]; i[j] = pi[base + j]; }
}

__global__ __launch_bounds__(256) void merge_parts_kernel(const float* pd, const int* pi, int* idxb) {
  int g = blockIdx.x * blockDim.x + threadIdx.x;
  if (g >= NB * NN1) return;
  int b = g / NN1, n1 = g - b * NN1;
#pragma unroll
  for (int typ = 0; typ < 2; ++typ) {
    float td[8], ud[8], md[8], vd[8];
    int ti[8], ui[8], mi[8], vi[8];
    loadlist_(pd, pi, b, 0, n1, typ, td, ti);
    loadlist_(pd, pi, b, 1, n1, typ, ud, ui);
    merge8_(td, ti, ud, ui);                 // 01
    loadlist_(pd, pi, b, 2, n1, typ, md, mi);
    loadlist_(pd, pi, b, 3, n1, typ, ud, ui);
    merge8_(md, mi, ud, ui);                 // 23
    merge8_(td, ti, md, mi);                 // 0123
    loadlist_(pd, pi, b, 4, n1, typ, md, mi);
    loadlist_(pd, pi, b, 5, n1, typ, ud, ui);
    merge8_(md, mi, ud, ui);                 // 45
    loadlist_(pd, pi, b, 6, n1, typ, vd, vi);
    loadlist_(pd, pi, b, 7, n1, typ, ud, ui);
    merge8_(vd, vi, ud, ui);                 // 67
    merge8_(md, mi, vd, vi);                 // 4567
    merge8_(td, ti, md, mi);                 // final
    size_t ob = (size_t)g * 16 + typ * 8;
#pragma unroll
    for (int j = 0; j < 8; ++j) idxb[ob + j] = ti[j];
  }
}

// ---------------- K5: fused GRU mapping (one wave per (b,n1)) ----------------
__global__ __launch_bounds__(256) void gru_kernel(
    const int* idxb, const float* x1t, const float* x2t,
    const float* p1r, const float* p1ro, const float* p1z,
    const float* p2r, const float* p2ro, const float* p2z,
    const float* wt,
    const float* br0, const float* br1, const float* br2,
    const float* bz0, const float* bz1, const float* bz2,
    const float* bh0, const float* bh1, const float* bh2,
    float* out) {
  __shared__ float dxs[4][16 * 4];
  __shared__ float Vs[4][64];
  __shared__ float Gs[4][16 * 64];
  __shared__ float As[4][16 * 64];
  __shared__ float Bs[4][16 * 64];
  __shared__ float R3s[4][16 * 64];
  __shared__ int idxs[4][16];

  int t = threadIdx.x;
  int w = t >> 6, l = t & 63;
  int b = blockIdx.y;
  int n1i = blockIdx.x * 4 + w;
  int rowbase = b * NN1 + n1i;

  float* dx = dxs[w]; float* V = Vs[w]; float* G = Gs[w];
  float* A = As[w]; float* Bb = Bs[w]; float* R3 = R3s[w];
  int* idxw = idxs[w];

  if (l < 16) idxw[l] = idxb[(size_t)rowbase * 16 + l];
  __syncthreads();
  if (l < 16) {
    float4 x1v = ((const float4*)x1t)[rowbase];
    float4 x2v = ((const float4*)x2t)[b * NN2 + idxw[l]];
    dx[l * 4 + 0] = x2v.x - x1v.x;
    dx[l * 4 + 1] = x2v.y - x1v.y;
    dx[l * 4 + 2] = x2v.z - x1v.z;
  }
  float pr  = p1r[(size_t)rowbase * 64 + l];
  float pro = p1ro[(size_t)rowbase * 64 + l];
  float pz  = p1z[(size_t)rowbase * 64 + l];
  __syncthreads();

  const float* Wr0t = wt + 6 * 4096;
  const float* Wr1t = wt + 7 * 4096;
  const float* Wr2t = wt + 8 * 4096;
  const float* Wz0t = wt + 9 * 4096;
  const float* Wz1t = wt + 10 * 4096;
  const float* Wz2t = wt + 11 * 4096;
  const float* Wh0t = wt + 12 * 4096;
  const float* Wh1t = wt + 13 * 4096;
  const float* Wh2t = wt + 14 * 4096;

  float wv[64];

  // ---- r branch ----
  for (int k = 0; k < 16; ++k)
    G[k * 64 + l] = p2r[((size_t)b * NN2 + idxw[k]) * 64 + l];
  __syncthreads();
  {
    float w0 = Wr0t[l], w1 = Wr0t[64 + l], w2 = Wr0t[128 + l];
    float b0 = br0[l];
#pragma unroll
    for (int k = 0; k < 16; ++k) {
      float pre = b0 + pr + G[k * 64 + l]
                + w0 * dx[k * 4 + 0] + w1 * dx[k * 4 + 1] + w2 * dx[k * 4 + 2];
      A[k * 64 + l] = leaky_(pre);
    }
  }
  __syncthreads();
#pragma unroll
  for (int c = 0; c < 64; ++c) wv[c] = Wr1t[c * 64 + l];
  {
    float b1 = br1[l];
    for (int k = 0; k < 16; ++k) {
      float acc = b1;
#pragma unroll
      for (int c4 = 0; c4 < 16; ++c4) {
        float4 a4 = *(const float4*)&A[k * 64 + c4 * 4];
        acc += wv[c4 * 4 + 0] * a4.x + wv[c4 * 4 + 1] * a4.y
             + wv[c4 * 4 + 2] * a4.z + wv[c4 * 4 + 3] * a4.w;
      }
      Bb[k * 64 + l] = leaky_(acc);
    }
  }
  __syncthreads();
#pragma unroll
  for (int c = 0; c < 64; ++c) wv[c] = Wr2t[c * 64 + l];
  {
    float b2 = br2[l];
    for (int k = 0; k < 16; ++k) {
      float acc = b2;
#pragma unroll
      for (int c4 = 0; c4 < 16; ++c4) {
        float4 a4 = *(const float4*)&Bb[k * 64 + c4 * 4];
        acc += wv[c4 * 4 + 0] * a4.x + wv[c4 * 4 + 1] * a4.y
             + wv[c4 * 4 + 2] * a4.z + wv[c4 * 4 + 3] * a4.w;
      }
      R3[k * 64 + l] = sigm_(acc);
    }
  }
  __syncthreads();

  // ---- z branch ----
  for (int k = 0; k < 16; ++k)
    G[k * 64 + l] = p2ro[((size_t)b * NN2 + idxw[k]) * 64 + l];
  __syncthreads();
  {
    float w0 = Wz0t[l], w1 = Wz0t[64 + l], w2 = Wz0t[128 + l];
    float b0 = bz0[l];
#pragma unroll
    for (int k = 0; k < 16; ++k) {
      float pre = b0 + pz + G[k * 64 + l]
                + w0 * dx[k * 4 + 0] + w1 * dx[k * 4 + 1] + w2 * dx[k * 4 + 2];
      A[k * 64 + l] = leaky_(pre);
    }
  }
  __syncthreads();
#pragma unroll
  for (int c = 0; c < 64; ++c) wv[c] = Wz1t[c * 64 + l];
  {
    float b1 = bz1[l];
    float zm = -INFINITY;
    for (int k = 0; k < 16; ++k) {
      float acc = b1;
#pragma unroll
      for (int c4 = 0; c4 < 16; ++c4) {
        float4 a4 = *(const float4*)&A[k * 64 + c4 * 4];
        acc += wv[c4 * 4 + 0] * a4.x + wv[c4 * 4 + 1] * a4.y
             + wv[c4 * 4 + 2] * a4.z + wv[c4 * 4 + 3] * a4.w;
      }
      zm = fmaxf(zm, leaky_(acc));
    }
    V[l] = zm;
  }
  __syncthreads();
  float z3;
  {
    float acc = bz2[l];
#pragma unroll
    for (int c4 = 0; c4 < 16; ++c4) {
      float4 v4 = *(const float4*)&V[c4 * 4];
      acc += Wz2t[(c4 * 4 + 0) * 64 + l] * v4.x + Wz2t[(c4 * 4 + 1) * 64 + l] * v4.y
           + Wz2t[(c4 * 4 + 2) * 64 + l] * v4.z + Wz2t[(c4 * 4 + 3) * 64 + l] * v4.w;
    }
    z3 = sigm_(acc);
  }
  __syncthreads();

  // ---- h branch ----
  for (int k = 0; k < 16; ++k)
    G[k * 64 + l] = p2z[((size_t)b * NN2 + idxw[k]) * 64 + l];
  __syncthreads();
  {
    float w0 = Wh0t[l], w1 = Wh0t[64 + l], w2 = Wh0t[128 + l];
    float b0 = bh0[l];
#pragma unroll
    for (int k = 0; k < 16; ++k) {
      float pre = b0 + R3[k * 64 + l] * pro + G[k * 64 + l]
                + w0 * dx[k * 4 + 0] + w1 * dx[k * 4 + 1] + w2 * dx[k * 4 + 2];
      A[k * 64 + l] = leaky_(pre);
    }
  }
  __syncthreads();
#pragma unroll
  for (int c = 0; c < 64; ++c) wv[c] = Wh1t[c * 64 + l];
  {
    float b1 = bh1[l];
    float hm = -INFINITY;
    for (int k = 0; k < 16; ++k) {
      float acc = b1;
#pragma unroll
      for (int c4 = 0; c4 < 16; ++c4) {
        float4 a4 = *(const float4*)&A[k * 64 + c4 * 4];
        acc += wv[c4 * 4 + 0] * a4.x + wv[c4 * 4 + 1] * a4.y
             + wv[c4 * 4 + 2] * a4.z + wv[c4 * 4 + 3] * a4.w;
      }
      hm = fmaxf(hm, leaky_(acc));
    }
    V[l] = hm;
  }
  __syncthreads();
  float h3;
  {
    float acc = bh2[l];
#pragma unroll
    for (int c4 = 0; c4 < 16; ++c4) {
      float4 v4 = *(const float4*)&V[c4 * 4];
      acc += Wh2t[(c4 * 4 + 0) * 64 + l] * v4.x + Wh2t[(c4 * 4 + 1) * 64 + l] * v4.y
           + Wh2t[(c4 * 4 + 2) * 64 + l] * v4.z + Wh2t[(c4 * 4 + 3) * 64 + l] * v4.w;
    }
    h3 = leaky_(acc);
  }

  out[((size_t)b * 64 + l) * NN1 + n1i] = (1.0f - z3) * pro + z3 * h3;
}

extern "C" void kernel_launch(void* const* d_in, const int* in_sizes, int n_in,
                              void* d_out, int out_size, void* d_ws, size_t ws_size,
                              hipStream_t stream) {
  (void)in_sizes; (void)n_in; (void)out_size; (void)ws_size;
  const float* xyz1    = (const float*)d_in[0];
  const float* xyz2    = (const float*)d_in[1];
  const float* points1 = (const float*)d_in[2];
  const float* points2 = (const float*)d_in[3];
  const float* knn1    = (const float*)d_in[4];
  const float* knn2    = (const float*)d_in[5];
  const float* Wfr   = (const float*)d_in[6];
  const float* Wfro  = (const float*)d_in[7];
  const float* Wfz   = (const float*)d_in[8];
  const float* Wfr2  = (const float*)d_in[9];
  const float* Wfro2 = (const float*)d_in[10];
  const float* Wfz2  = (const float*)d_in[11];
  const float* Wr0 = (const float*)d_in[12]; const float* br0 = (const float*)d_in[13];
  const float* Wr1 = (const float*)d_in[14]; const float* br1 = (const float*)d_in[15];
  const float* Wr2 = (const float*)d_in[16]; const float* br2 = (const float*)d_in[17];
  const float* Wz0 = (const float*)d_in[18]; const float* bz0 = (const float*)d_in[19];
  const float* Wz1 = (const float*)d_in[20]; const float* bz1 = (const float*)d_in[21];
  const float* Wz2 = (const float*)d_in[22]; const float* bz2 = (const float*)d_in[23];
  const float* Wh0 = (const float*)d_in[24]; const float* bh0 = (const float*)d_in[25];
  const float* Wh1 = (const float*)d_in[26]; const float* bh1 = (const float*)d_in[27];
  const float* Wh2 = (const float*)d_in[28]; const float* bh2 = (const float*)d_in[29];

  float* W = (float*)d_ws;
  size_t o = 0;
  float* f1n = W + o; o += (size_t)NB * NN1 * 64;
  float* f2n = W + o; o += (size_t)NB * NN2 * 64;
  float* x1t = W + o; o += (size_t)NB * NN1 * 4;
  float* x2t = W + o; o += (size_t)NB * NN2 * 4;
  float* p1r = W + o; o += (size_t)NB * NN1 * 64;
  float* p1ro = W + o; o += (size_t)NB * NN1 * 64;
  float* p1z = W + o; o += (size_t)NB * NN1 * 64;
  float* p2r = W + o; o += (size_t)NB * NN2 * 64;
  float* p2ro = W + o; o += (size_t)NB * NN2 * 64;
  float* p2z = W + o; o += (size_t)NB * NN2 * 64;
  float* wt = W + o; o += (size_t)15 * 4096;
  float* pd = W + o; o += (size_t)NB * NPART * NN1 * 16;
  int* pi = (int*)(W + o); o += (size_t)NB * NPART * NN1 * 16;
  int* idxb = (int*)(W + o); o += (size_t)NB * NN1 * 16;

  float* out = (float*)d_out;

  hipLaunchKernelGGL(prep_w_kernel, dim3(15), dim3(256), 0, stream,
                     Wfr, Wfro, Wfz, Wfr2, Wfro2, Wfz2,
                     Wr0, Wr1, Wr2, Wz0, Wz1, Wz2, Wh0, Wh1, Wh2, wt);
  hipLaunchKernelGGL(prep_side_kernel, dim3(NN1 / 64, NB), dim3(64), 0, stream,
                     knn1, xyz1, f1n, x1t, NN1);
  hipLaunchKernelGGL(prep_side_kernel, dim3(NN2 / 64, NB), dim3(64), 0, stream,
                     knn2, xyz2, f2n, x2t, NN2);
  hipLaunchKernelGGL(fuse_kernel, dim3(NN1 / 4, NB), dim3(256), 0, stream,
                     points1, wt + 0 * 4096, wt + 1 * 4096, wt + 2 * 4096,
                     p1r, p1ro, p1z, NN1);
  hipLaunchKernelGGL(fuse_kernel, dim3(NN2 / 4, NB), dim3(256), 0, stream,
                     points2, wt + 3 * 4096, wt + 4 * 4096, wt + 5 * 4096,
                     p2r, p2ro, p2z, NN2);
  hipLaunchKernelGGL(knn_kernel, dim3(NN1 / 64, NPART, NB), dim3(256), 0, stream,
                     f1n, f2n, x1t, x2t, pd, pi);
  hipLaunchKernelGGL(merge_parts_kernel, dim3((NB * NN1 + 255) / 256), dim3(256), 0, stream,
                     pd, pi, idxb);
  hipLaunchKernelGGL(gru_kernel, dim3(NN1 / 4, NB), dim3(256), 0, stream,
                     idxb, x1t, x2t, p1r, p1ro, p1z, p2r, p2ro, p2z, wt,
                     br0, br1, br2, bz0, bz1, bz2, bh0, bh1, bh2, out);
}

// Round 3
// 1217.617 us; speedup vs baseline: 1.3005x; 1.3005x over previous
//
#include <hip/hip_runtime.h>
#include <math.h>

#define NB 2
#define NN1 4096
#define NN2 8192
#define NPART 8
#define LEAKK 0.1f

__device__ __forceinline__ float leaky_(float x) { return fmaxf(x, LEAKK * x); }
__device__ __forceinline__ float sigm_(float x) { return 1.0f / (1.0f + __expf(-x)); }

// insert (d,i) into sorted-ascending-(d,i)-lex list of 8 kept in registers
__device__ __forceinline__ void ins8_(float d, int i, float* ld, int* li) {
  bool better = (d < ld[7]) || (d == ld[7] && i < li[7]);
  if (better) {
#pragma unroll
    for (int j = 0; j < 8; ++j) {
      bool lt = (d < ld[j]) || (d == ld[j] && i < li[j]);
      if (lt) { float td = ld[j]; int ti = li[j]; ld[j] = d; li[j] = i; d = td; i = ti; }
    }
  }
}

// merge two sorted 8-lists, keep first 8 (result in a)
__device__ __forceinline__ void merge8_(float* ad, int* ai, float* bd, int* bi) {
  float rd[8]; int ri[8];
#pragma unroll
  for (int s = 0; s < 8; ++s) {
    bool ta = (ad[0] < bd[0]) || (ad[0] == bd[0] && ai[0] < bi[0]);
    rd[s] = ta ? ad[0] : bd[0];
    ri[s] = ta ? ai[0] : bi[0];
#pragma unroll
    for (int j = 0; j < 7; ++j) {
      ad[j] = ta ? ad[j + 1] : ad[j];
      ai[j] = ta ? ai[j + 1] : ai[j];
      bd[j] = ta ? bd[j] : bd[j + 1];
      bi[j] = ta ? bi[j] : bi[j + 1];
    }
  }
#pragma unroll
  for (int j = 0; j < 8; ++j) { ad[j] = rd[j]; ai[j] = ri[j]; }
}

// ---------------- K0: transpose all 15 weight matrices into ws ----------------
__global__ void prep_w_kernel(const float* s0, const float* s1, const float* s2,
                              const float* s3, const float* s4, const float* s5,
                              const float* s6, const float* s7, const float* s8,
                              const float* s9, const float* s10, const float* s11,
                              const float* s12, const float* s13, const float* s14,
                              float* wt) {
  const float* srcs[15] = {s0, s1, s2, s3, s4, s5, s6, s7, s8, s9, s10, s11, s12, s13, s14};
  int bid = blockIdx.x;
  const float* src = srcs[bid];
  int cols = (bid < 6) ? 64 : (((bid - 6) % 3 == 0) ? 3 : 64);
  float* dst = wt + bid * 4096;
  for (int e = threadIdx.x; e < 64 * cols; e += blockDim.x) {
    int o = e / cols, c = e - o * cols;
    dst[c * 64 + o] = src[e];
  }
}

// ---------------- K1: transpose+normalize knn features, pack xyz+|x|^2 ----------------
__global__ __launch_bounds__(64) void prep_side_kernel(const float* knn, const float* xyz,
                                                       float* fdst, float* xdst, int N) {
  __shared__ float T[64 * 65];
  __shared__ float rs[64];
  int b = blockIdx.y;
  int n0 = blockIdx.x * 64;
  int l = threadIdx.x;
  const float* kb = knn + (size_t)b * 64 * N + n0;
  for (int c = 0; c < 64; ++c) T[c * 65 + l] = kb[(size_t)c * N + l];
  __syncthreads();
  float s = 0.f;
  for (int c = 0; c < 64; ++c) { float v = T[c * 65 + l]; s += v * v; }
  rs[l] = 1.0f / sqrtf(s + 1e-8f);
  __syncthreads();
  for (int i = 0; i < 64; ++i)
    fdst[(size_t)(b * N + n0 + i) * 64 + l] = T[l * 65 + i] * rs[i];
  const float* xb = xyz + (size_t)b * 3 * N + n0;
  float x = xb[l], y = xb[N + l], z = xb[2 * N + l];
  ((float4*)xdst)[b * N + n0 + l] = make_float4(x, y, z, x * x + y * y + z * z);
}

// ---------------- K2: three fused 1x1 conv matvecs ----------------
__global__ __launch_bounds__(256) void fuse_kernel(const float* pts, const float* wt0,
                                                   const float* wt1, const float* wt2,
                                                   float* d0, float* d1, float* d2, int N) {
  int b = blockIdx.y;
  int w = threadIdx.x >> 6, l = threadIdx.x & 63;
  int n = blockIdx.x * 4 + w;
  const float* pb = pts + (size_t)b * 64 * N + n;
  float a0 = 0.f, a1 = 0.f, a2 = 0.f;
  for (int c = 0; c < 64; ++c) {
    float p = pb[(size_t)c * N];
    a0 += p * wt0[c * 64 + l];
    a1 += p * wt1[c * 64 + l];
    a2 += p * wt2[c * 64 + l];
  }
  size_t ob = (size_t)(b * N + n) * 64 + l;
  d0[ob] = a0; d1[ob] = a1; d2[ob] = a2;
}

// ---------------- K3: dual-metric partitioned KNN (v3) ----------------
// v1 parallel per-thread register top-8 + row-global threshold filter +
// 128-wide chunks with 4x8 register blocking + in-register euclidean.
// Block: 256 threads, 64 rows, partition of 1024 cols in 8 chunks of 128.
__global__ __launch_bounds__(256) void knn_kernel(const float* f1n, const float* f2n,
                                                  const float* x1t, const float* x2t,
                                                  float* pd, int* pi) {
  __shared__ float f1t[64 * 64];      // [k][row]
  __shared__ float f2d[64 * 129];     // chunk: [k][cand] (k*128+cand), then dtile [r][c] (r*129+c)
  __shared__ float x1x[64], x1y[64], x1z[64], x1w[64];
  __shared__ float x2s[128 * 4];      // [cand][4]
  __shared__ float thrc4[4 * 64];     // [quarter][row]
  __shared__ float thre4[4 * 64];

  int t = threadIdx.x;
  int lane = t & 63, w = t >> 6;
  int n0 = blockIdx.x * 64;
  int part = (int)blockIdx.y;
  int b = (int)blockIdx.z;

  // stage f1 tile (k-major) + x1 (SoA)
  {
    const float* f1row = f1n + (size_t)(b * NN1 + n0 + lane) * 64;
#pragma unroll
    for (int pass = 0; pass < 4; ++pass) {
      int c0 = pass * 16 + w * 4;
      float4 v = *(const float4*)(f1row + c0);
      f1t[(c0 + 0) * 64 + lane] = v.x;
      f1t[(c0 + 1) * 64 + lane] = v.y;
      f1t[(c0 + 2) * 64 + lane] = v.z;
      f1t[(c0 + 3) * 64 + lane] = v.w;
    }
    if (t < 64) {
      float4 v = ((const float4*)x1t)[b * NN1 + n0 + t];
      x1x[t] = v.x; x1y[t] = v.y; x1z[t] = v.z; x1w[t] = v.w;
    }
    if (t >= 64 && t < 192) {
      int j = t - 64;
      thrc4[j] = INFINITY; thrc4[128 + j] = INFINITY;
      thre4[j] = INFINITY; thre4[128 + j] = INFINITY;
    }
  }

  float cd[8], ed[8]; int ci[8], ei[8];
#pragma unroll
  for (int j = 0; j < 8; ++j) { cd[j] = INFINITY; ed[j] = INFINITY; ci[j] = 0x7fffffff; ei[j] = 0x7fffffff; }

  int ty = t >> 4, tx = t & 15;   // matmul: rows ty*4.., cols {tx*4.., 64+tx*4..}
  __syncthreads();

  for (int ch = 0; ch < 8; ++ch) {
    int cc = part * 1024 + ch * 128;

    // stage f2 chunk (k-major) + x2
    {
      int cand = t & 127;
      int sb = (t >> 7) * 8;
      const float* src = f2n + (size_t)(b * NN2 + cc + cand) * 64 + sb * 4;
#pragma unroll
      for (int p = 0; p < 8; ++p) {
        float4 v = *(const float4*)(src + p * 4);
        int c0 = (sb + p) * 4;
        f2d[(c0 + 0) * 128 + cand] = v.x;
        f2d[(c0 + 1) * 128 + cand] = v.y;
        f2d[(c0 + 2) * 128 + cand] = v.z;
        f2d[(c0 + 3) * 128 + cand] = v.w;
      }
      if (t < 128) ((float4*)x2s)[t] = ((const float4*)x2t)[b * NN2 + cc + t];
    }
    __syncthreads();

    // 64x128 cos-similarity tile, 4 rows x 8 cols per thread (split-column)
    float acc0[4][4], acc1[4][4];
#pragma unroll
    for (int i = 0; i < 4; ++i)
#pragma unroll
      for (int j = 0; j < 4; ++j) { acc0[i][j] = 0.f; acc1[i][j] = 0.f; }

#pragma unroll 2
    for (int k = 0; k < 64; ++k) {
      float4 a  = *(const float4*)&f1t[k * 64 + ty * 4];
      float4 b0 = *(const float4*)&f2d[k * 128 + tx * 4];
      float4 b1 = *(const float4*)&f2d[k * 128 + 64 + tx * 4];
      acc0[0][0] += a.x * b0.x; acc0[0][1] += a.x * b0.y; acc0[0][2] += a.x * b0.z; acc0[0][3] += a.x * b0.w;
      acc0[1][0] += a.y * b0.x; acc0[1][1] += a.y * b0.y; acc0[1][2] += a.y * b0.z; acc0[1][3] += a.y * b0.w;
      acc0[2][0] += a.z * b0.x; acc0[2][1] += a.z * b0.y; acc0[2][2] += a.z * b0.z; acc0[2][3] += a.z * b0.w;
      acc0[3][0] += a.w * b0.x; acc0[3][1] += a.w * b0.y; acc0[3][2] += a.w * b0.z; acc0[3][3] += a.w * b0.w;
      acc1[0][0] += a.x * b1.x; acc1[0][1] += a.x * b1.y; acc1[0][2] += a.x * b1.z; acc1[0][3] += a.x * b1.w;
      acc1[1][0] += a.y * b1.x; acc1[1][1] += a.y * b1.y; acc1[1][2] += a.y * b1.z; acc1[1][3] += a.y * b1.w;
      acc1[2][0] += a.z * b1.x; acc1[2][1] += a.z * b1.y; acc1[2][2] += a.z * b1.z; acc1[2][3] += a.z * b1.w;
      acc1[3][0] += a.w * b1.x; acc1[3][1] += a.w * b1.y; acc1[3][2] += a.w * b1.z; acc1[3][3] += a.w * b1.w;
    }
    __syncthreads();   // all waves done reading f2d (k-major view)

    // write cos distances into dtile[r][c] = f2d[r*129 + c]
#pragma unroll
    for (int i = 0; i < 4; ++i) {
      int r = ty * 4 + i;
#pragma unroll
      for (int j = 0; j < 4; ++j) {
        f2d[r * 129 + tx * 4 + j]      = 1.f - acc0[i][j];
        f2d[r * 129 + 64 + tx * 4 + j] = 1.f - acc1[i][j];
      }
    }
    __syncthreads();

    // selection: thread (row=lane, quarter=w) scans cols [w*32, w*32+32)
    {
      float thrC = fminf(fminf(thrc4[lane], thrc4[64 + lane]),
                         fminf(thrc4[128 + lane], thrc4[192 + lane]));
      float thrE = fminf(fminf(thre4[lane], thre4[64 + lane]),
                         fminf(thre4[128 + lane], thre4[192 + lane]));
      float xx = x1x[lane], xy = x1y[lane], xz = x1z[lane], xw = x1w[lane];
      const float* drow = &f2d[lane * 129 + w * 32];
      const float4* x2q = ((const float4*)x2s) + w * 32;
#pragma unroll 4
      for (int j = 0; j < 32; ++j) {
        int gi = cc + w * 32 + j;
        float dv = drow[j];
        if (dv <= thrC) ins8_(dv, gi, cd, ci);
        float4 xv = x2q[j];
        float d3 = xw + xv.w - 2.f * (xx * xv.x + xy * xv.y + xz * xv.z);
        if (d3 <= thrE) ins8_(d3, gi, ed, ei);
      }
      // publish this thread's current 8th for the row threshold
      thrc4[w * 64 + lane] = cd[7];
      thre4[w * 64 + lane] = ed[7];
    }
    __syncthreads();   // thresholds visible; dtile free for restaging
  }

  // in-block merge of the 4 per-quarter lists per row (reuse f1t/f2d as staging)
  {
    float* Lcd = f1t;                    // 64*33 = 2112 floats
    int*   Lci = (int*)f2d;              // 2112
    float* Led = f2d + 2112;             // 2112
    int*   Lei = (int*)(f2d + 4224);     // 2112  (total 6336 <= 8256)
#pragma unroll
    for (int j = 0; j < 8; ++j) {
      Lcd[lane * 33 + w * 8 + j] = cd[j];
      Lci[lane * 33 + w * 8 + j] = ci[j];
      Led[lane * 33 + w * 8 + j] = ed[j];
      Lei[lane * 33 + w * 8 + j] = ei[j];
    }
    __syncthreads();
    if (t < 128) {
      int typ = t >> 6, r = t & 63;
      const float* Ld = typ ? Led : Lcd;
      const int* Li = typ ? Lei : Lci;
      float a0d[8], a1d[8], a2d[8], a3d[8];
      int a0i[8], a1i[8], a2i[8], a3i[8];
#pragma unroll
      for (int j = 0; j < 8; ++j) {
        a0d[j] = Ld[r * 33 + 0 + j];  a0i[j] = Li[r * 33 + 0 + j];
        a1d[j] = Ld[r * 33 + 8 + j];  a1i[j] = Li[r * 33 + 8 + j];
        a2d[j] = Ld[r * 33 + 16 + j]; a2i[j] = Li[r * 33 + 16 + j];
        a3d[j] = Ld[r * 33 + 24 + j]; a3i[j] = Li[r * 33 + 24 + j];
      }
      merge8_(a0d, a0i, a1d, a1i);
      merge8_(a2d, a2i, a3d, a3i);
      merge8_(a0d, a0i, a2d, a2i);
      size_t base = ((size_t)(b * NPART + part) * NN1 + n0 + r) * 16 + typ * 8;
#pragma unroll
      for (int j = 0; j < 8; ++j) { pd[base + j] = a0d[j]; pi[base + j] = a0i[j]; }
    }
  }
}

// ---------------- K4: merge the NPART partial lists -> final idx ----------------
__device__ __forceinline__ void loadlist_(const float* pd, const int* pi, int b, int p, int n1,
                                          int typ, float* d, int* i) {
  size_t base = ((size_t)(b * NPART + p) * NN1 + n1) * 16 + typ * 8;
#pragma unroll
  for (int j = 0; j < 8; ++j) { d[j] = pd[base + j]; i[j] = pi[base + j]; }
}

__global__ __launch_bounds__(256) void merge_parts_kernel(const float* pd, const int* pi, int* idxb) {
  int g = blockIdx.x * blockDim.x + threadIdx.x;
  if (g >= NB * NN1) return;
  int b = g / NN1, n1 = g - b * NN1;
#pragma unroll
  for (int typ = 0; typ < 2; ++typ) {
    float td[8], ud[8], md[8], vd[8];
    int ti[8], ui[8], mi[8], vi[8];
    loadlist_(pd, pi, b, 0, n1, typ, td, ti);
    loadlist_(pd, pi, b, 1, n1, typ, ud, ui);
    merge8_(td, ti, ud, ui);                 // 01
    loadlist_(pd, pi, b, 2, n1, typ, md, mi);
    loadlist_(pd, pi, b, 3, n1, typ, ud, ui);
    merge8_(md, mi, ud, ui);                 // 23
    merge8_(td, ti, md, mi);                 // 0123
    loadlist_(pd, pi, b, 4, n1, typ, md, mi);
    loadlist_(pd, pi, b, 5, n1, typ, ud, ui);
    merge8_(md, mi, ud, ui);                 // 45
    loadlist_(pd, pi, b, 6, n1, typ, vd, vi);
    loadlist_(pd, pi, b, 7, n1, typ, ud, ui);
    merge8_(vd, vi, ud, ui);                 // 67
    merge8_(md, mi, vd, vi);                 // 4567
    merge8_(td, ti, md, mi);                 // final
    size_t ob = (size_t)g * 16 + typ * 8;
#pragma unroll
    for (int j = 0; j < 8; ++j) idxb[ob + j] = ti[j];
  }
}

// ---------------- K5: fused GRU mapping (one wave per (b,n1)) ----------------
__global__ __launch_bounds__(256) void gru_kernel(
    const int* idxb, const float* x1t, const float* x2t,
    const float* p1r, const float* p1ro, const float* p1z,
    const float* p2r, const float* p2ro, const float* p2z,
    const float* wt,
    const float* br0, const float* br1, const float* br2,
    const float* bz0, const float* bz1, const float* bz2,
    const float* bh0, const float* bh1, const float* bh2,
    float* out) {
  __shared__ float dxs[4][16 * 4];
  __shared__ float Vs[4][64];
  __shared__ float Gs[4][16 * 64];
  __shared__ float As[4][16 * 64];
  __shared__ float Bs[4][16 * 64];
  __shared__ float R3s[4][16 * 64];
  __shared__ int idxs[4][16];

  int t = threadIdx.x;
  int w = t >> 6, l = t & 63;
  int b = blockIdx.y;
  int n1i = blockIdx.x * 4 + w;
  int rowbase = b * NN1 + n1i;

  float* dx = dxs[w]; float* V = Vs[w]; float* G = Gs[w];
  float* A = As[w]; float* Bb = Bs[w]; float* R3 = R3s[w];
  int* idxw = idxs[w];

  if (l < 16) idxw[l] = idxb[(size_t)rowbase * 16 + l];
  __syncthreads();
  if (l < 16) {
    float4 x1v = ((const float4*)x1t)[rowbase];
    float4 x2v = ((const float4*)x2t)[b * NN2 + idxw[l]];
    dx[l * 4 + 0] = x2v.x - x1v.x;
    dx[l * 4 + 1] = x2v.y - x1v.y;
    dx[l * 4 + 2] = x2v.z - x1v.z;
  }
  float pr  = p1r[(size_t)rowbase * 64 + l];
  float pro = p1ro[(size_t)rowbase * 64 + l];
  float pz  = p1z[(size_t)rowbase * 64 + l];
  __syncthreads();

  const float* Wr0t = wt + 6 * 4096;
  const float* Wr1t = wt + 7 * 4096;
  const float* Wr2t = wt + 8 * 4096;
  const float* Wz0t = wt + 9 * 4096;
  const float* Wz1t = wt + 10 * 4096;
  const float* Wz2t = wt + 11 * 4096;
  const float* Wh0t = wt + 12 * 4096;
  const float* Wh1t = wt + 13 * 4096;
  const float* Wh2t = wt + 14 * 4096;

  float wv[64];

  // ---- r branch ----
  for (int k = 0; k < 16; ++k)
    G[k * 64 + l] = p2r[((size_t)b * NN2 + idxw[k]) * 64 + l];
  __syncthreads();
  {
    float w0 = Wr0t[l], w1 = Wr0t[64 + l], w2 = Wr0t[128 + l];
    float b0 = br0[l];
#pragma unroll
    for (int k = 0; k < 16; ++k) {
      float pre = b0 + pr + G[k * 64 + l]
                + w0 * dx[k * 4 + 0] + w1 * dx[k * 4 + 1] + w2 * dx[k * 4 + 2];
      A[k * 64 + l] = leaky_(pre);
    }
  }
  __syncthreads();
#pragma unroll
  for (int c = 0; c < 64; ++c) wv[c] = Wr1t[c * 64 + l];
  {
    float b1 = br1[l];
    for (int k = 0; k < 16; ++k) {
      float acc = b1;
#pragma unroll
      for (int c4 = 0; c4 < 16; ++c4) {
        float4 a4 = *(const float4*)&A[k * 64 + c4 * 4];
        acc += wv[c4 * 4 + 0] * a4.x + wv[c4 * 4 + 1] * a4.y
             + wv[c4 * 4 + 2] * a4.z + wv[c4 * 4 + 3] * a4.w;
      }
      Bb[k * 64 + l] = leaky_(acc);
    }
  }
  __syncthreads();
#pragma unroll
  for (int c = 0; c < 64; ++c) wv[c] = Wr2t[c * 64 + l];
  {
    float b2 = br2[l];
    for (int k = 0; k < 16; ++k) {
      float acc = b2;
#pragma unroll
      for (int c4 = 0; c4 < 16; ++c4) {
        float4 a4 = *(const float4*)&Bb[k * 64 + c4 * 4];
        acc += wv[c4 * 4 + 0] * a4.x + wv[c4 * 4 + 1] * a4.y
             + wv[c4 * 4 + 2] * a4.z + wv[c4 * 4 + 3] * a4.w;
      }
      R3[k * 64 + l] = sigm_(acc);
    }
  }
  __syncthreads();

  // ---- z branch ----
  for (int k = 0; k < 16; ++k)
    G[k * 64 + l] = p2ro[((size_t)b * NN2 + idxw[k]) * 64 + l];
  __syncthreads();
  {
    float w0 = Wz0t[l], w1 = Wz0t[64 + l], w2 = Wz0t[128 + l];
    float b0 = bz0[l];
#pragma unroll
    for (int k = 0; k < 16; ++k) {
      float pre = b0 + pz + G[k * 64 + l]
                + w0 * dx[k * 4 + 0] + w1 * dx[k * 4 + 1] + w2 * dx[k * 4 + 2];
      A[k * 64 + l] = leaky_(pre);
    }
  }
  __syncthreads();
#pragma unroll
  for (int c = 0; c < 64; ++c) wv[c] = Wz1t[c * 64 + l];
  {
    float b1 = bz1[l];
    float zm = -INFINITY;
    for (int k = 0; k < 16; ++k) {
      float acc = b1;
#pragma unroll
      for (int c4 = 0; c4 < 16; ++c4) {
        float4 a4 = *(const float4*)&A[k * 64 + c4 * 4];
        acc += wv[c4 * 4 + 0] * a4.x + wv[c4 * 4 + 1] * a4.y
             + wv[c4 * 4 + 2] * a4.z + wv[c4 * 4 + 3] * a4.w;
      }
      zm = fmaxf(zm, leaky_(acc));
    }
    V[l] = zm;
  }
  __syncthreads();
  float z3;
  {
    float acc = bz2[l];
#pragma unroll
    for (int c4 = 0; c4 < 16; ++c4) {
      float4 v4 = *(const float4*)&V[c4 * 4];
      acc += Wz2t[(c4 * 4 + 0) * 64 + l] * v4.x + Wz2t[(c4 * 4 + 1) * 64 + l] * v4.y
           + Wz2t[(c4 * 4 + 2) * 64 + l] * v4.z + Wz2t[(c4 * 4 + 3) * 64 + l] * v4.w;
    }
    z3 = sigm_(acc);
  }
  __syncthreads();

  // ---- h branch ----
  for (int k = 0; k < 16; ++k)
    G[k * 64 + l] = p2z[((size_t)b * NN2 + idxw[k]) * 64 + l];
  __syncthreads();
  {
    float w0 = Wh0t[l], w1 = Wh0t[64 + l], w2 = Wh0t[128 + l];
    float b0 = bh0[l];
#pragma unroll
    for (int k = 0; k < 16; ++k) {
      float pre = b0 + R3[k * 64 + l] * pro + G[k * 64 + l]
                + w0 * dx[k * 4 + 0] + w1 * dx[k * 4 + 1] + w2 * dx[k * 4 + 2];
      A[k * 64 + l] = leaky_(pre);
    }
  }
  __syncthreads();
#pragma unroll
  for (int c = 0; c < 64; ++c) wv[c] = Wh1t[c * 64 + l];
  {
    float b1 = bh1[l];
    float hm = -INFINITY;
    for (int k = 0; k < 16; ++k) {
      float acc = b1;
#pragma unroll
      for (int c4 = 0; c4 < 16; ++c4) {
        float4 a4 = *(const float4*)&A[k * 64 + c4 * 4];
        acc += wv[c4 * 4 + 0] * a4.x + wv[c4 * 4 + 1] * a4.y
             + wv[c4 * 4 + 2] * a4.z + wv[c4 * 4 + 3] * a4.w;
      }
      hm = fmaxf(hm, leaky_(acc));
    }
    V[l] = hm;
  }
  __syncthreads();
  float h3;
  {
    float acc = bh2[l];
#pragma unroll
    for (int c4 = 0; c4 < 16; ++c4) {
      float4 v4 = *(const float4*)&V[c4 * 4];
      acc += Wh2t[(c4 * 4 + 0) * 64 + l] * v4.x + Wh2t[(c4 * 4 + 1) * 64 + l] * v4.y
           + Wh2t[(c4 * 4 + 2) * 64 + l] * v4.z + Wh2t[(c4 * 4 + 3) * 64 + l] * v4.w;
    }
    h3 = leaky_(acc);
  }

  out[((size_t)b * 64 + l) * NN1 + n1i] = (1.0f - z3) * pro + z3 * h3;
}

extern "C" void kernel_launch(void* const* d_in, const int* in_sizes, int n_in,
                              void* d_out, int out_size, void* d_ws, size_t ws_size,
                              hipStream_t stream) {
  (void)in_sizes; (void)n_in; (void)out_size; (void)ws_size;
  const float* xyz1    = (const float*)d_in[0];
  const float* xyz2    = (const float*)d_in[1];
  const float* points1 = (const float*)d_in[2];
  const float* points2 = (const float*)d_in[3];
  const float* knn1    = (const float*)d_in[4];
  const float* knn2    = (const float*)d_in[5];
  const float* Wfr   = (const float*)d_in[6];
  const float* Wfro  = (const float*)d_in[7];
  const float* Wfz   = (const float*)d_in[8];
  const float* Wfr2  = (const float*)d_in[9];
  const float* Wfro2 = (const float*)d_in[10];
  const float* Wfz2  = (const float*)d_in[11];
  const float* Wr0 = (const float*)d_in[12]; const float* br0 = (const float*)d_in[13];
  const float* Wr1 = (const float*)d_in[14]; const float* br1 = (const float*)d_in[15];
  const float* Wr2 = (const float*)d_in[16]; const float* br2 = (const float*)d_in[17];
  const float* Wz0 = (const float*)d_in[18]; const float* bz0 = (const float*)d_in[19];
  const float* Wz1 = (const float*)d_in[20]; const float* bz1 = (const float*)d_in[21];
  const float* Wz2 = (const float*)d_in[22]; const float* bz2 = (const float*)d_in[23];
  const float* Wh0 = (const float*)d_in[24]; const float* bh0 = (const float*)d_in[25];
  const float* Wh1 = (const float*)d_in[26]; const float* bh1 = (const float*)d_in[27];
  const float* Wh2 = (const float*)d_in[28]; const float* bh2 = (const float*)d_in[29];

  float* W = (float*)d_ws;
  size_t o = 0;
  float* f1n = W + o; o += (size_t)NB * NN1 * 64;
  float* f2n = W + o; o += (size_t)NB * NN2 * 64;
  float* x1t = W + o; o += (size_t)NB * NN1 * 4;
  float* x2t = W + o; o += (size_t)NB * NN2 * 4;
  float* p1r = W + o; o += (size_t)NB * NN1 * 64;
  float* p1ro = W + o; o += (size_t)NB * NN1 * 64;
  float* p1z = W + o; o += (size_t)NB * NN1 * 64;
  float* p2r = W + o; o += (size_t)NB * NN2 * 64;
  float* p2ro = W + o; o += (size_t)NB * NN2 * 64;
  float* p2z = W + o; o += (size_t)NB * NN2 * 64;
  float* wt = W + o; o += (size_t)15 * 4096;
  float* pd = W + o; o += (size_t)NB * NPART * NN1 * 16;
  int* pi = (int*)(W + o); o += (size_t)NB * NPART * NN1 * 16;
  int* idxb = (int*)(W + o); o += (size_t)NB * NN1 * 16;

  float* out = (float*)d_out;

  hipLaunchKernelGGL(prep_w_kernel, dim3(15), dim3(256), 0, stream,
                     Wfr, Wfro, Wfz, Wfr2, Wfro2, Wfz2,
                     Wr0, Wr1, Wr2, Wz0, Wz1, Wz2, Wh0, Wh1, Wh2, wt);
  hipLaunchKernelGGL(prep_side_kernel, dim3(NN1 / 64, NB), dim3(64), 0, stream,
                     knn1, xyz1, f1n, x1t, NN1);
  hipLaunchKernelGGL(prep_side_kernel, dim3(NN2 / 64, NB), dim3(64), 0, stream,
                     knn2, xyz2, f2n, x2t, NN2);
  hipLaunchKernelGGL(fuse_kernel, dim3(NN1 / 4, NB), dim3(256), 0, stream,
                     points1, wt + 0 * 4096, wt + 1 * 4096, wt + 2 * 4096,
                     p1r, p1ro, p1z, NN1);
  hipLaunchKernelGGL(fuse_kernel, dim3(NN2 / 4, NB), dim3(256), 0, stream,
                     points2, wt + 3 * 4096, wt + 4 * 4096, wt + 5 * 4096,
                     p2r, p2ro, p2z, NN2);
  hipLaunchKernelGGL(knn_kernel, dim3(NN1 / 64, NPART, NB), dim3(256), 0, stream,
                     f1n, f2n, x1t, x2t, pd, pi);
  hipLaunchKernelGGL(merge_parts_kernel, dim3((NB * NN1 + 255) / 256), dim3(256), 0, stream,
                     pd, pi, idxb);
  hipLaunchKernelGGL(gru_kernel, dim3(NN1 / 4, NB), dim3(256), 0, stream,
                     idxb, x1t, x2t, p1r, p1ro, p1z, p2r, p2ro, p2z, wt,
                     br0, br1, br2, bz0, bz1, bz2, bh0, bh1, bh2, out);
}

// Round 4
// 607.818 us; speedup vs baseline: 2.6053x; 2.0033x over previous
//
#include <hip/hip_runtime.h>
#include <math.h>

#define NB 2
#define NN1 4096
#define NN2 8192
#define NPART 8
#define LEAKK 0.1f

typedef unsigned long long u64k;

__device__ __forceinline__ float leaky_(float x) { return fmaxf(x, LEAKK * x); }
__device__ __forceinline__ float sigm_(float x) { return 1.0f / (1.0f + __expf(-x)); }

// insert key into sorted-ascending 8-list (caller guarantees k < q[7])
__device__ __forceinline__ void insq_(u64k k, u64k* q) {
#pragma unroll
  for (int j = 7; j > 0; --j)
    q[j] = (k < q[j - 1]) ? q[j - 1] : ((k < q[j]) ? k : q[j]);
  q[0] = (k < q[0]) ? k : q[0];
}

// merge two sorted-ascending 8-lists, keep smallest 8 in a
__device__ __forceinline__ void merge8q_(u64k* a, u64k* b) {
  u64k r[8];
#pragma unroll
  for (int s = 0; s < 8; ++s) {
    bool ta = a[0] < b[0];
    r[s] = ta ? a[0] : b[0];
#pragma unroll
    for (int j = 0; j < 7; ++j) {
      a[j] = ta ? a[j + 1] : a[j];
      b[j] = ta ? b[j] : b[j + 1];
    }
  }
#pragma unroll
  for (int j = 0; j < 8; ++j) a[j] = r[j];
}

// ---------------- K0: transpose all 15 weight matrices into ws ----------------
__global__ void prep_w_kernel(const float* s0, const float* s1, const float* s2,
                              const float* s3, const float* s4, const float* s5,
                              const float* s6, const float* s7, const float* s8,
                              const float* s9, const float* s10, const float* s11,
                              const float* s12, const float* s13, const float* s14,
                              float* wt) {
  const float* srcs[15] = {s0, s1, s2, s3, s4, s5, s6, s7, s8, s9, s10, s11, s12, s13, s14};
  int bid = blockIdx.x;
  const float* src = srcs[bid];
  int cols = (bid < 6) ? 64 : (((bid - 6) % 3 == 0) ? 3 : 64);
  float* dst = wt + bid * 4096;
  for (int e = threadIdx.x; e < 64 * cols; e += blockDim.x) {
    int o = e / cols, c = e - o * cols;
    dst[c * 64 + o] = src[e];
  }
}

// ---------------- K1: transpose+normalize knn features, pack xyz+|x|^2 ----------------
__global__ __launch_bounds__(64) void prep_side_kernel(const float* knn, const float* xyz,
                                                       float* fdst, float* xdst, int N) {
  __shared__ float T[64 * 65];
  __shared__ float rs[64];
  int b = blockIdx.y;
  int n0 = blockIdx.x * 64;
  int l = threadIdx.x;
  const float* kb = knn + (size_t)b * 64 * N + n0;
  for (int c = 0; c < 64; ++c) T[c * 65 + l] = kb[(size_t)c * N + l];
  __syncthreads();
  float s = 0.f;
  for (int c = 0; c < 64; ++c) { float v = T[c * 65 + l]; s += v * v; }
  rs[l] = 1.0f / sqrtf(s + 1e-8f);
  __syncthreads();
  for (int i = 0; i < 64; ++i)
    fdst[(size_t)(b * N + n0 + i) * 64 + l] = T[l * 65 + i] * rs[i];
  const float* xb = xyz + (size_t)b * 3 * N + n0;
  float x = xb[l], y = xb[N + l], z = xb[2 * N + l];
  ((float4*)xdst)[b * N + n0 + l] = make_float4(x, y, z, x * x + y * y + z * z);
}

// ---------------- K2: three fused 1x1 conv matvecs ----------------
__global__ __launch_bounds__(256) void fuse_kernel(const float* pts, const float* wt0,
                                                   const float* wt1, const float* wt2,
                                                   float* d0, float* d1, float* d2, int N) {
  int b = blockIdx.y;
  int w = threadIdx.x >> 6, l = threadIdx.x & 63;
  int n = blockIdx.x * 4 + w;
  const float* pb = pts + (size_t)b * 64 * N + n;
  float a0 = 0.f, a1 = 0.f, a2 = 0.f;
  for (int c = 0; c < 64; ++c) {
    float p = pb[(size_t)c * N];
    a0 += p * wt0[c * 64 + l];
    a1 += p * wt1[c * 64 + l];
    a2 += p * wt2[c * 64 + l];
  }
  size_t ob = (size_t)(b * N + n) * 64 + l;
  d0[ob] = a0; d1[ob] = a1; d2[ob] = a2;
}

// ---------------- K3: dual-metric partitioned KNN (v4: u64 keys, 3 blocks/CU) ----------------
// Block: 256 threads, 64 rows, partition of 1024 cols in 8 chunks of 128.
// One aliased LDS arena (52480 B -> 3 blocks/CU).
__global__ __launch_bounds__(256, 3) void knn_kernel(const float* f1n, const float* f2n,
                                                     const float* x1t, const float* x2t,
                                                     u64k* pq) {
  __shared__ __align__(16) float SH[13120];
  float* f1t = SH;               // 4096  : [k][row]
  float* f2d = SH + 4096;        // 8256  : chunk [k][cand] (k*128+cand) then dtile [r][129]
  float* x1x = SH + 12352;       // 64
  float* x1y = SH + 12416;
  float* x1z = SH + 12480;
  float* x1w = SH + 12544;
  float* x2s = SH + 12608;       // 512 : [cand][4]

  int t = threadIdx.x;
  int lane = t & 63, w = t >> 6;
  int n0 = blockIdx.x * 64;
  int part = (int)blockIdx.y;
  int b = (int)blockIdx.z;

  // stage f1 tile (k-major) + x1 (SoA)
  {
    const float* f1row = f1n + (size_t)(b * NN1 + n0 + lane) * 64;
#pragma unroll
    for (int pass = 0; pass < 4; ++pass) {
      int c0 = pass * 16 + w * 4;
      float4 v = *(const float4*)(f1row + c0);
      f1t[(c0 + 0) * 64 + lane] = v.x;
      f1t[(c0 + 1) * 64 + lane] = v.y;
      f1t[(c0 + 2) * 64 + lane] = v.z;
      f1t[(c0 + 3) * 64 + lane] = v.w;
    }
    if (t < 64) {
      float4 v = ((const float4*)x1t)[b * NN1 + n0 + t];
      x1x[t] = v.x; x1y[t] = v.y; x1z[t] = v.z; x1w[t] = v.w;
    }
  }

  u64k cq[8], eq[8];
#pragma unroll
  for (int j = 0; j < 8; ++j) { cq[j] = ~0ull; eq[j] = ~0ull; }

  int ty = t >> 4, tx = t & 15;
  __syncthreads();
  float xx = x1x[lane], xy = x1y[lane], xz = x1z[lane], xw = x1w[lane];

  for (int ch = 0; ch < 8; ++ch) {
    int cc = part * 1024 + ch * 128;

    // stage f2 chunk (k-major) + x2
    {
      int cand = t & 127;
      int sb = (t >> 7) * 8;
      const float* src = f2n + (size_t)(b * NN2 + cc + cand) * 64 + sb * 4;
#pragma unroll
      for (int p = 0; p < 8; ++p) {
        float4 v = *(const float4*)(src + p * 4);
        int c0 = (sb + p) * 4;
        f2d[(c0 + 0) * 128 + cand] = v.x;
        f2d[(c0 + 1) * 128 + cand] = v.y;
        f2d[(c0 + 2) * 128 + cand] = v.z;
        f2d[(c0 + 3) * 128 + cand] = v.w;
      }
      if (t < 128) ((float4*)x2s)[t] = ((const float4*)x2t)[b * NN2 + cc + t];
    }
    __syncthreads();

    // 64x128 cos-similarity tile, 4 rows x 8 cols per thread (split-column)
    float acc0[4][4], acc1[4][4];
#pragma unroll
    for (int i = 0; i < 4; ++i)
#pragma unroll
      for (int j = 0; j < 4; ++j) { acc0[i][j] = 0.f; acc1[i][j] = 0.f; }

#pragma unroll 2
    for (int k = 0; k < 64; ++k) {
      float4 a  = *(const float4*)&f1t[k * 64 + ty * 4];
      float4 b0 = *(const float4*)&f2d[k * 128 + tx * 4];
      float4 b1 = *(const float4*)&f2d[k * 128 + 64 + tx * 4];
      acc0[0][0] += a.x * b0.x; acc0[0][1] += a.x * b0.y; acc0[0][2] += a.x * b0.z; acc0[0][3] += a.x * b0.w;
      acc0[1][0] += a.y * b0.x; acc0[1][1] += a.y * b0.y; acc0[1][2] += a.y * b0.z; acc0[1][3] += a.y * b0.w;
      acc0[2][0] += a.z * b0.x; acc0[2][1] += a.z * b0.y; acc0[2][2] += a.z * b0.z; acc0[2][3] += a.z * b0.w;
      acc0[3][0] += a.w * b0.x; acc0[3][1] += a.w * b0.y; acc0[3][2] += a.w * b0.z; acc0[3][3] += a.w * b0.w;
      acc1[0][0] += a.x * b1.x; acc1[0][1] += a.x * b1.y; acc1[0][2] += a.x * b1.z; acc1[0][3] += a.x * b1.w;
      acc1[1][0] += a.y * b1.x; acc1[1][1] += a.y * b1.y; acc1[1][2] += a.y * b1.z; acc1[1][3] += a.y * b1.w;
      acc1[2][0] += a.z * b1.x; acc1[2][1] += a.z * b1.y; acc1[2][2] += a.z * b1.z; acc1[2][3] += a.z * b1.w;
      acc1[3][0] += a.w * b1.x; acc1[3][1] += a.w * b1.y; acc1[3][2] += a.w * b1.z; acc1[3][3] += a.w * b1.w;
    }
    __syncthreads();   // all waves done reading k-major f2d

    // write clamped cos distances into dtile[r][c] = f2d[r*129 + c]
#pragma unroll
    for (int i = 0; i < 4; ++i) {
      int r = ty * 4 + i;
#pragma unroll
      for (int j = 0; j < 4; ++j) {
        f2d[r * 129 + tx * 4 + j]      = fmaxf(1.f - acc0[i][j], 0.f);
        f2d[r * 129 + 64 + tx * 4 + j] = fmaxf(1.f - acc1[i][j], 0.f);
      }
    }
    __syncthreads();

    // selection: thread (row=lane, quarter=w) scans cols [w*32, w*32+32)
    {
      const float* drow = &f2d[lane * 129 + w * 32];
      const float4* x2q = ((const float4*)x2s) + w * 32;
#pragma unroll 4
      for (int j = 0; j < 32; ++j) {
        unsigned gi = cc + w * 32 + j;
        float dv = drow[j];
        u64k kc = ((u64k)__float_as_uint(dv) << 32) | gi;
        if (kc < cq[7]) insq_(kc, cq);
        float4 xv = x2q[j];
        float d3 = fmaxf(xw + xv.w - 2.f * (xx * xv.x + xy * xv.y + xz * xv.z), 0.f);
        u64k ke = ((u64k)__float_as_uint(d3) << 32) | gi;
        if (ke < eq[7]) insq_(ke, eq);
      }
    }
    __syncthreads();   // before next chunk restages f2d / x2s
  }

  // in-block merge of the 4 per-quarter lists per row (alias whole arena)
  {
    u64k* Lc = (u64k*)SH;           // 64*33 u64
    u64k* Le = ((u64k*)SH) + 2112;  // 64*33 u64  (total 33792 B <= 52480)
#pragma unroll
    for (int j = 0; j < 8; ++j) {
      Lc[lane * 33 + w * 8 + j] = cq[j];
      Le[lane * 33 + w * 8 + j] = eq[j];
    }
    __syncthreads();
    if (t < 128) {
      int typ = t >> 6, r = t & 63;
      const u64k* L = typ ? Le : Lc;
      u64k a0[8], a1[8], a2[8], a3[8];
#pragma unroll
      for (int j = 0; j < 8; ++j) {
        a0[j] = L[r * 33 + 0 + j];
        a1[j] = L[r * 33 + 8 + j];
        a2[j] = L[r * 33 + 16 + j];
        a3[j] = L[r * 33 + 24 + j];
      }
      merge8q_(a0, a1);
      merge8q_(a2, a3);
      merge8q_(a0, a2);
      size_t base = ((size_t)((b * NPART + part) * NN1) + n0 + r) * 16 + typ * 8;
#pragma unroll
      for (int j = 0; j < 8; ++j) pq[base + j] = a0[j];
    }
  }
}

// ---------------- K4: merge the NPART partial lists -> final idx ----------------
__device__ __forceinline__ void loadq_(const u64k* pq, int b, int p, int n1, int typ, u64k* q) {
  size_t base = ((size_t)((b * NPART + p) * NN1) + n1) * 16 + typ * 8;
#pragma unroll
  for (int j = 0; j < 8; ++j) q[j] = pq[base + j];
}

__global__ __launch_bounds__(256) void merge_parts_kernel(const u64k* pq, int* idxb) {
  int g = blockIdx.x * blockDim.x + threadIdx.x;
  if (g >= NB * NN1) return;
  int b = g / NN1, n1 = g - b * NN1;
#pragma unroll
  for (int typ = 0; typ < 2; ++typ) {
    u64k A[8], B[8], C[8], D[8];
    loadq_(pq, b, 0, n1, typ, A);
    loadq_(pq, b, 1, n1, typ, B);
    merge8q_(A, B);
    loadq_(pq, b, 2, n1, typ, C);
    loadq_(pq, b, 3, n1, typ, D);
    merge8q_(C, D);
    merge8q_(A, C);
    loadq_(pq, b, 4, n1, typ, B);
    loadq_(pq, b, 5, n1, typ, C);
    merge8q_(B, C);
    loadq_(pq, b, 6, n1, typ, C);
    loadq_(pq, b, 7, n1, typ, D);
    merge8q_(C, D);
    merge8q_(B, C);
    merge8q_(A, B);
    size_t ob = (size_t)g * 16 + typ * 8;
#pragma unroll
    for (int j = 0; j < 8; ++j) idxb[ob + j] = (int)(A[j] & 0xffffffffull);
  }
}

// ---------------- K5: fused GRU mapping v2 (one wave per (b,n1), no barriers) ----------------
// 64->64 layer, c-tiled weights (16 regs), A read via LDS broadcast.
__device__ __forceinline__ void mat64_(const float* src, const float* Wt, float bias,
                                       int l, float* acc) {
#pragma unroll
  for (int k = 0; k < 16; ++k) acc[k] = bias;
#pragma unroll
  for (int cb = 0; cb < 4; ++cb) {
    float wv[16];
#pragma unroll
    for (int i = 0; i < 16; ++i) wv[i] = Wt[(cb * 16 + i) * 64 + l];
#pragma unroll
    for (int k = 0; k < 16; ++k) {
      float4 a0 = *(const float4*)&src[k * 64 + cb * 16 + 0];
      float4 a1 = *(const float4*)&src[k * 64 + cb * 16 + 4];
      float4 a2 = *(const float4*)&src[k * 64 + cb * 16 + 8];
      float4 a3 = *(const float4*)&src[k * 64 + cb * 16 + 12];
      acc[k] += wv[0] * a0.x + wv[1] * a0.y + wv[2] * a0.z + wv[3] * a0.w
              + wv[4] * a1.x + wv[5] * a1.y + wv[6] * a1.z + wv[7] * a1.w
              + wv[8] * a2.x + wv[9] * a2.y + wv[10] * a2.z + wv[11] * a2.w
              + wv[12] * a3.x + wv[13] * a3.y + wv[14] * a3.z + wv[15] * a3.w;
    }
  }
}

// 64->64 matvec from a 64-vector in LDS
__device__ __forceinline__ float matv64_(const float* v, const float* Wt, float bias, int l) {
  float acc = bias;
#pragma unroll
  for (int cb = 0; cb < 4; ++cb) {
    float4 v0 = *(const float4*)&v[cb * 16 + 0];
    float4 v1 = *(const float4*)&v[cb * 16 + 4];
    float4 v2 = *(const float4*)&v[cb * 16 + 8];
    float4 v3 = *(const float4*)&v[cb * 16 + 12];
    acc += Wt[(cb * 16 + 0) * 64 + l] * v0.x + Wt[(cb * 16 + 1) * 64 + l] * v0.y
         + Wt[(cb * 16 + 2) * 64 + l] * v0.z + Wt[(cb * 16 + 3) * 64 + l] * v0.w
         + Wt[(cb * 16 + 4) * 64 + l] * v1.x + Wt[(cb * 16 + 5) * 64 + l] * v1.y
         + Wt[(cb * 16 + 6) * 64 + l] * v1.z + Wt[(cb * 16 + 7) * 64 + l] * v1.w
         + Wt[(cb * 16 + 8) * 64 + l] * v2.x + Wt[(cb * 16 + 9) * 64 + l] * v2.y
         + Wt[(cb * 16 + 10) * 64 + l] * v2.z + Wt[(cb * 16 + 11) * 64 + l] * v2.w
         + Wt[(cb * 16 + 12) * 64 + l] * v3.x + Wt[(cb * 16 + 13) * 64 + l] * v3.y
         + Wt[(cb * 16 + 14) * 64 + l] * v3.z + Wt[(cb * 16 + 15) * 64 + l] * v3.w;
  }
  return acc;
}

__global__ __launch_bounds__(256, 3) void gru_kernel(
    const int* idxb, const float* x1t, const float* x2t,
    const float* p1r, const float* p1ro, const float* p1z,
    const float* p2r, const float* p2ro, const float* p2z,
    const float* wt,
    const float* br0, const float* br1, const float* br2,
    const float* bz0, const float* bz1, const float* bz2,
    const float* bh0, const float* bh1, const float* bh2,
    float* out) {
  __shared__ float As[4][16 * 64];
  __shared__ float Bs[4][16 * 64];
  __shared__ float Rs[4][16 * 64];
  __shared__ float Vs[4][64];
  __shared__ float dxs[4][16 * 4];
  __shared__ int idxs[4][16];

  int t = threadIdx.x;
  int w = t >> 6, l = t & 63;
  int b = blockIdx.y;
  int n1i = blockIdx.x * 4 + w;
  int rowbase = b * NN1 + n1i;

  float* A = As[w]; float* Bf = Bs[w]; float* R3 = Rs[w];
  float* V = Vs[w]; float* dx = dxs[w];
  int* idxw = idxs[w];

  if (l < 16) {
    int gi = idxb[(size_t)rowbase * 16 + l];
    idxw[l] = gi;
    float4 x1v = ((const float4*)x1t)[rowbase];
    float4 x2v = ((const float4*)x2t)[b * NN2 + gi];
    dx[l * 4 + 0] = x2v.x - x1v.x;
    dx[l * 4 + 1] = x2v.y - x1v.y;
    dx[l * 4 + 2] = x2v.z - x1v.z;
    dx[l * 4 + 3] = 0.f;
  }
  float pr  = p1r[(size_t)rowbase * 64 + l];
  float pro = p1ro[(size_t)rowbase * 64 + l];
  float pz  = p1z[(size_t)rowbase * 64 + l];

  const float* Wr0t = wt + 6 * 4096;
  const float* Wr1t = wt + 7 * 4096;
  const float* Wr2t = wt + 8 * 4096;
  const float* Wz0t = wt + 9 * 4096;
  const float* Wz1t = wt + 10 * 4096;
  const float* Wz2t = wt + 11 * 4096;
  const float* Wh0t = wt + 12 * 4096;
  const float* Wh1t = wt + 13 * 4096;
  const float* Wh2t = wt + 14 * 4096;

  float acc[16];

  // ---- r branch ----
  {
    float w0 = Wr0t[l], w1 = Wr0t[64 + l], w2 = Wr0t[128 + l], b0 = br0[l];
#pragma unroll
    for (int k = 0; k < 16; ++k) {
      int gk = idxw[k];
      float g = p2r[((size_t)b * NN2 + gk) * 64 + l];
      float4 dxk = *(const float4*)&dx[k * 4];
      A[k * 64 + l] = leaky_(b0 + pr + g + w0 * dxk.x + w1 * dxk.y + w2 * dxk.z);
    }
  }
  mat64_(A, Wr1t, br1[l], l, acc);
#pragma unroll
  for (int k = 0; k < 16; ++k) Bf[k * 64 + l] = leaky_(acc[k]);
  mat64_(Bf, Wr2t, br2[l], l, acc);
#pragma unroll
  for (int k = 0; k < 16; ++k) R3[k * 64 + l] = sigm_(acc[k]);

  // ---- z branch ----
  {
    float w0 = Wz0t[l], w1 = Wz0t[64 + l], w2 = Wz0t[128 + l], b0 = bz0[l];
#pragma unroll
    for (int k = 0; k < 16; ++k) {
      int gk = idxw[k];
      float g = p2ro[((size_t)b * NN2 + gk) * 64 + l];
      float4 dxk = *(const float4*)&dx[k * 4];
      A[k * 64 + l] = leaky_(b0 + pz + g + w0 * dxk.x + w1 * dxk.y + w2 * dxk.z);
    }
  }
  mat64_(A, Wz1t, bz1[l], l, acc);
  {
    float zm = -INFINITY;
#pragma unroll
    for (int k = 0; k < 16; ++k) zm = fmaxf(zm, leaky_(acc[k]));
    V[l] = zm;
  }
  float z3 = sigm_(matv64_(V, Wz2t, bz2[l], l));

  // ---- h branch ----
  {
    float w0 = Wh0t[l], w1 = Wh0t[64 + l], w2 = Wh0t[128 + l], b0 = bh0[l];
#pragma unroll
    for (int k = 0; k < 16; ++k) {
      int gk = idxw[k];
      float g = p2z[((size_t)b * NN2 + gk) * 64 + l];
      float4 dxk = *(const float4*)&dx[k * 4];
      A[k * 64 + l] = leaky_(b0 + R3[k * 64 + l] * pro + g + w0 * dxk.x + w1 * dxk.y + w2 * dxk.z);
    }
  }
  mat64_(A, Wh1t, bh1[l], l, acc);
  {
    float hm = -INFINITY;
#pragma unroll
    for (int k = 0; k < 16; ++k) hm = fmaxf(hm, leaky_(acc[k]));
    V[l] = hm;
  }
  float h3 = leaky_(matv64_(V, Wh2t, bh2[l], l));

  out[((size_t)b * 64 + l) * NN1 + n1i] = (1.0f - z3) * pro + z3 * h3;
}

extern "C" void kernel_launch(void* const* d_in, const int* in_sizes, int n_in,
                              void* d_out, int out_size, void* d_ws, size_t ws_size,
                              hipStream_t stream) {
  (void)in_sizes; (void)n_in; (void)out_size; (void)ws_size;
  const float* xyz1    = (const float*)d_in[0];
  const float* xyz2    = (const float*)d_in[1];
  const float* points1 = (const float*)d_in[2];
  const float* points2 = (const float*)d_in[3];
  const float* knn1    = (const float*)d_in[4];
  const float* knn2    = (const float*)d_in[5];
  const float* Wfr   = (const float*)d_in[6];
  const float* Wfro  = (const float*)d_in[7];
  const float* Wfz   = (const float*)d_in[8];
  const float* Wfr2  = (const float*)d_in[9];
  const float* Wfro2 = (const float*)d_in[10];
  const float* Wfz2  = (const float*)d_in[11];
  const float* Wr0 = (const float*)d_in[12]; const float* br0 = (const float*)d_in[13];
  const float* Wr1 = (const float*)d_in[14]; const float* br1 = (const float*)d_in[15];
  const float* Wr2 = (const float*)d_in[16]; const float* br2 = (const float*)d_in[17];
  const float* Wz0 = (const float*)d_in[18]; const float* bz0 = (const float*)d_in[19];
  const float* Wz1 = (const float*)d_in[20]; const float* bz1 = (const float*)d_in[21];
  const float* Wz2 = (const float*)d_in[22]; const float* bz2 = (const float*)d_in[23];
  const float* Wh0 = (const float*)d_in[24]; const float* bh0 = (const float*)d_in[25];
  const float* Wh1 = (const float*)d_in[26]; const float* bh1 = (const float*)d_in[27];
  const float* Wh2 = (const float*)d_in[28]; const float* bh2 = (const float*)d_in[29];

  float* W = (float*)d_ws;
  size_t o = 0;
  float* f1n = W + o; o += (size_t)NB * NN1 * 64;
  float* f2n = W + o; o += (size_t)NB * NN2 * 64;
  float* x1t = W + o; o += (size_t)NB * NN1 * 4;
  float* x2t = W + o; o += (size_t)NB * NN2 * 4;
  float* p1r = W + o; o += (size_t)NB * NN1 * 64;
  float* p1ro = W + o; o += (size_t)NB * NN1 * 64;
  float* p1z = W + o; o += (size_t)NB * NN1 * 64;
  float* p2r = W + o; o += (size_t)NB * NN2 * 64;
  float* p2ro = W + o; o += (size_t)NB * NN2 * 64;
  float* p2z = W + o; o += (size_t)NB * NN2 * 64;
  float* wt = W + o; o += (size_t)15 * 4096;
  u64k* pq = (u64k*)(W + o); o += (size_t)2 * NB * NPART * NN1 * 16;  // u64 = 2 floats
  int* idxb = (int*)(W + o); o += (size_t)NB * NN1 * 16;

  float* out = (float*)d_out;

  hipLaunchKernelGGL(prep_w_kernel, dim3(15), dim3(256), 0, stream,
                     Wfr, Wfro, Wfz, Wfr2, Wfro2, Wfz2,
                     Wr0, Wr1, Wr2, Wz0, Wz1, Wz2, Wh0, Wh1, Wh2, wt);
  hipLaunchKernelGGL(prep_side_kernel, dim3(NN1 / 64, NB), dim3(64), 0, stream,
                     knn1, xyz1, f1n, x1t, NN1);
  hipLaunchKernelGGL(prep_side_kernel, dim3(NN2 / 64, NB), dim3(64), 0, stream,
                     knn2, xyz2, f2n, x2t, NN2);
  hipLaunchKernelGGL(fuse_kernel, dim3(NN1 / 4, NB), dim3(256), 0, stream,
                     points1, wt + 0 * 4096, wt + 1 * 4096, wt + 2 * 4096,
                     p1r, p1ro, p1z, NN1);
  hipLaunchKernelGGL(fuse_kernel, dim3(NN2 / 4, NB), dim3(256), 0, stream,
                     points2, wt + 3 * 4096, wt + 4 * 4096, wt + 5 * 4096,
                     p2r, p2ro, p2z, NN2);
  hipLaunchKernelGGL(knn_kernel, dim3(NN1 / 64, NPART, NB), dim3(256), 0, stream,
                     f1n, f2n, x1t, x2t, pq);
  hipLaunchKernelGGL(merge_parts_kernel, dim3((NB * NN1 + 255) / 256), dim3(256), 0, stream,
                     pq, idxb);
  hipLaunchKernelGGL(gru_kernel, dim3(NN1 / 4, NB), dim3(256), 0, stream,
                     idxb, x1t, x2t, p1r, p1ro, p1z, p2r, p2ro, p2z, wt,
                     br0, br1, br2, bz0, bz1, bz2, bh0, bh1, bh2, out);
}

// Round 5
// 578.895 us; speedup vs baseline: 2.7355x; 1.0500x over previous
//
#include <hip/hip_runtime.h>
#include <math.h>

#define NB 2
#define NN1 4096
#define NN2 8192
#define NPART 16
#define PARTSZ (NN2 / NPART)     // 512
#define NCHUNK (PARTSZ / 128)    // 4
#define LEAKK 0.1f
#define GPAD 68

typedef unsigned long long u64k;

__device__ __forceinline__ float leaky_(float x) { return fmaxf(x, LEAKK * x); }
__device__ __forceinline__ float sigm_(float x) { return 1.0f / (1.0f + __expf(-x)); }

// insert key into sorted-ascending 8-list (caller guarantees k < q[7])
__device__ __forceinline__ void insq_(u64k k, u64k* q) {
#pragma unroll
  for (int j = 7; j > 0; --j)
    q[j] = (k < q[j - 1]) ? q[j - 1] : ((k < q[j]) ? k : q[j]);
  q[0] = (k < q[0]) ? k : q[0];
}

// merge two sorted-ascending 8-lists, keep smallest 8 in a
__device__ __forceinline__ void merge8q_(u64k* a, u64k* b) {
  u64k r[8];
#pragma unroll
  for (int s = 0; s < 8; ++s) {
    bool ta = a[0] < b[0];
    r[s] = ta ? a[0] : b[0];
#pragma unroll
    for (int j = 0; j < 7; ++j) {
      a[j] = ta ? a[j + 1] : a[j];
      b[j] = ta ? b[j] : b[j + 1];
    }
  }
#pragma unroll
  for (int j = 0; j < 8; ++j) a[j] = r[j];
}

// ---------------- K0: transpose all 15 weight matrices into ws ----------------
__global__ void prep_w_kernel(const float* s0, const float* s1, const float* s2,
                              const float* s3, const float* s4, const float* s5,
                              const float* s6, const float* s7, const float* s8,
                              const float* s9, const float* s10, const float* s11,
                              const float* s12, const float* s13, const float* s14,
                              float* wt) {
  const float* srcs[15] = {s0, s1, s2, s3, s4, s5, s6, s7, s8, s9, s10, s11, s12, s13, s14};
  int bid = blockIdx.x;
  const float* src = srcs[bid];
  int cols = (bid < 6) ? 64 : (((bid - 6) % 3 == 0) ? 3 : 64);
  float* dst = wt + bid * 4096;
  for (int e = threadIdx.x; e < 64 * cols; e += blockDim.x) {
    int o = e / cols, c = e - o * cols;
    dst[c * 64 + o] = src[e];
  }
}

// ---------------- K1: transpose+normalize knn features, pack xyz+|x|^2 (v2: 256 thr) ----
__global__ __launch_bounds__(256) void prep_side_kernel(const float* knn, const float* xyz,
                                                        float* fdst, float* xdst, int N) {
  __shared__ float T[64 * 65];
  __shared__ float ps[4 * 64];
  int b = blockIdx.y;
  int n0 = blockIdx.x * 64;
  int t = threadIdx.x, w = t >> 6, l = t & 63;
  const float* kb = knn + (size_t)b * 64 * N + n0;
#pragma unroll
  for (int i = 0; i < 16; ++i) {
    int c = w * 16 + i;
    T[c * 65 + l] = kb[(size_t)c * N + l];
  }
  __syncthreads();
  float s = 0.f;
#pragma unroll
  for (int i = 0; i < 16; ++i) { float v = T[(w * 16 + i) * 65 + l]; s += v * v; }
  ps[w * 64 + l] = s;
  __syncthreads();
#pragma unroll
  for (int i = 0; i < 16; ++i) {
    int p = w * 16 + i;
    float rsum = ps[p] + ps[64 + p] + ps[128 + p] + ps[192 + p];
    float rs = 1.0f / sqrtf(rsum + 1e-8f);
    fdst[(size_t)(b * N + n0 + p) * 64 + l] = T[l * 65 + p] * rs;
  }
  if (t < 64) {
    const float* xb = xyz + (size_t)b * 3 * N + n0;
    float x = xb[t], y = xb[N + t], z = xb[2 * N + t];
    ((float4*)xdst)[b * N + n0 + t] = make_float4(x, y, z, x * x + y * y + z * z);
  }
}

// ---------------- K2: three fused 1x1 conv matvecs ----------------
__global__ __launch_bounds__(256) void fuse_kernel(const float* pts, const float* wt0,
                                                   const float* wt1, const float* wt2,
                                                   float* d0, float* d1, float* d2, int N) {
  int b = blockIdx.y;
  int w = threadIdx.x >> 6, l = threadIdx.x & 63;
  int n = blockIdx.x * 4 + w;
  const float* pb = pts + (size_t)b * 64 * N + n;
  float a0 = 0.f, a1 = 0.f, a2 = 0.f;
  for (int c = 0; c < 64; ++c) {
    float p = pb[(size_t)c * N];
    a0 += p * wt0[c * 64 + l];
    a1 += p * wt1[c * 64 + l];
    a2 += p * wt2[c * 64 + l];
  }
  size_t ob = (size_t)(b * N + n) * 64 + l;
  d0[ob] = a0; d1[ob] = a1; d2[ob] = a2;
}

// ---------------- K3: dual-metric partitioned KNN (v5: NPART=16 for tail util) --------
__global__ __launch_bounds__(256, 3) void knn_kernel(const float* f1n, const float* f2n,
                                                     const float* x1t, const float* x2t,
                                                     u64k* pq) {
  __shared__ __align__(16) float SH[13120];
  float* f1t = SH;               // 4096  : [k][row]
  float* f2d = SH + 4096;        // 8256  : chunk [k][cand] (k*128+cand) then dtile [r][129]
  float* x1x = SH + 12352;
  float* x1y = SH + 12416;
  float* x1z = SH + 12480;
  float* x1w = SH + 12544;
  float* x2s = SH + 12608;       // 512 : [cand][4]

  int t = threadIdx.x;
  int lane = t & 63, w = t >> 6;
  int n0 = blockIdx.x * 64;
  int part = (int)blockIdx.y;
  int b = (int)blockIdx.z;

  {
    const float* f1row = f1n + (size_t)(b * NN1 + n0 + lane) * 64;
#pragma unroll
    for (int pass = 0; pass < 4; ++pass) {
      int c0 = pass * 16 + w * 4;
      float4 v = *(const float4*)(f1row + c0);
      f1t[(c0 + 0) * 64 + lane] = v.x;
      f1t[(c0 + 1) * 64 + lane] = v.y;
      f1t[(c0 + 2) * 64 + lane] = v.z;
      f1t[(c0 + 3) * 64 + lane] = v.w;
    }
    if (t < 64) {
      float4 v = ((const float4*)x1t)[b * NN1 + n0 + t];
      x1x[t] = v.x; x1y[t] = v.y; x1z[t] = v.z; x1w[t] = v.w;
    }
  }

  u64k cq[8], eq[8];
#pragma unroll
  for (int j = 0; j < 8; ++j) { cq[j] = ~0ull; eq[j] = ~0ull; }

  int ty = t >> 4, tx = t & 15;
  __syncthreads();
  float xx = x1x[lane], xy = x1y[lane], xz = x1z[lane], xw = x1w[lane];

  for (int ch = 0; ch < NCHUNK; ++ch) {
    int cc = part * PARTSZ + ch * 128;

    {
      int cand = t & 127;
      int sb = (t >> 7) * 8;
      const float* src = f2n + (size_t)(b * NN2 + cc + cand) * 64 + sb * 4;
#pragma unroll
      for (int p = 0; p < 8; ++p) {
        float4 v = *(const float4*)(src + p * 4);
        int c0 = (sb + p) * 4;
        f2d[(c0 + 0) * 128 + cand] = v.x;
        f2d[(c0 + 1) * 128 + cand] = v.y;
        f2d[(c0 + 2) * 128 + cand] = v.z;
        f2d[(c0 + 3) * 128 + cand] = v.w;
      }
      if (t < 128) ((float4*)x2s)[t] = ((const float4*)x2t)[b * NN2 + cc + t];
    }
    __syncthreads();

    float acc0[4][4], acc1[4][4];
#pragma unroll
    for (int i = 0; i < 4; ++i)
#pragma unroll
      for (int j = 0; j < 4; ++j) { acc0[i][j] = 0.f; acc1[i][j] = 0.f; }

#pragma unroll 2
    for (int k = 0; k < 64; ++k) {
      float4 a  = *(const float4*)&f1t[k * 64 + ty * 4];
      float4 b0 = *(const float4*)&f2d[k * 128 + tx * 4];
      float4 b1 = *(const float4*)&f2d[k * 128 + 64 + tx * 4];
      acc0[0][0] += a.x * b0.x; acc0[0][1] += a.x * b0.y; acc0[0][2] += a.x * b0.z; acc0[0][3] += a.x * b0.w;
      acc0[1][0] += a.y * b0.x; acc0[1][1] += a.y * b0.y; acc0[1][2] += a.y * b0.z; acc0[1][3] += a.y * b0.w;
      acc0[2][0] += a.z * b0.x; acc0[2][1] += a.z * b0.y; acc0[2][2] += a.z * b0.z; acc0[2][3] += a.z * b0.w;
      acc0[3][0] += a.w * b0.x; acc0[3][1] += a.w * b0.y; acc0[3][2] += a.w * b0.z; acc0[3][3] += a.w * b0.w;
      acc1[0][0] += a.x * b1.x; acc1[0][1] += a.x * b1.y; acc1[0][2] += a.x * b1.z; acc1[0][3] += a.x * b1.w;
      acc1[1][0] += a.y * b1.x; acc1[1][1] += a.y * b1.y; acc1[1][2] += a.y * b1.z; acc1[1][3] += a.y * b1.w;
      acc1[2][0] += a.z * b1.x; acc1[2][1] += a.z * b1.y; acc1[2][2] += a.z * b1.z; acc1[2][3] += a.z * b1.w;
      acc1[3][0] += a.w * b1.x; acc1[3][1] += a.w * b1.y; acc1[3][2] += a.w * b1.z; acc1[3][3] += a.w * b1.w;
    }
    __syncthreads();

#pragma unroll
    for (int i = 0; i < 4; ++i) {
      int r = ty * 4 + i;
#pragma unroll
      for (int j = 0; j < 4; ++j) {
        f2d[r * 129 + tx * 4 + j]      = fmaxf(1.f - acc0[i][j], 0.f);
        f2d[r * 129 + 64 + tx * 4 + j] = fmaxf(1.f - acc1[i][j], 0.f);
      }
    }
    __syncthreads();

    {
      const float* drow = &f2d[lane * 129 + w * 32];
      const float4* x2q = ((const float4*)x2s) + w * 32;
#pragma unroll 4
      for (int j = 0; j < 32; ++j) {
        unsigned gi = cc + w * 32 + j;
        float dv = drow[j];
        u64k kc = ((u64k)__float_as_uint(dv) << 32) | gi;
        if (kc < cq[7]) insq_(kc, cq);
        float4 xv = x2q[j];
        float d3 = fmaxf(xw + xv.w - 2.f * (xx * xv.x + xy * xv.y + xz * xv.z), 0.f);
        u64k ke = ((u64k)__float_as_uint(d3) << 32) | gi;
        if (ke < eq[7]) insq_(ke, eq);
      }
    }
    __syncthreads();
  }

  {
    u64k* Lc = (u64k*)SH;
    u64k* Le = ((u64k*)SH) + 2112;
#pragma unroll
    for (int j = 0; j < 8; ++j) {
      Lc[lane * 33 + w * 8 + j] = cq[j];
      Le[lane * 33 + w * 8 + j] = eq[j];
    }
    __syncthreads();
    if (t < 128) {
      int typ = t >> 6, r = t & 63;
      const u64k* L = typ ? Le : Lc;
      u64k a0[8], a1[8], a2[8], a3[8];
#pragma unroll
      for (int j = 0; j < 8; ++j) {
        a0[j] = L[r * 33 + 0 + j];
        a1[j] = L[r * 33 + 8 + j];
        a2[j] = L[r * 33 + 16 + j];
        a3[j] = L[r * 33 + 24 + j];
      }
      merge8q_(a0, a1);
      merge8q_(a2, a3);
      merge8q_(a0, a2);
      size_t base = ((size_t)((b * NPART + part) * NN1) + n0 + r) * 16 + typ * 8;
#pragma unroll
      for (int j = 0; j < 8; ++j) pq[base + j] = a0[j];
    }
  }
}

// ---------------- K4: merge the NPART partial lists -> final idx ----------------
__device__ __forceinline__ void loadq_(const u64k* pq, int b, int p, int n1, int typ, u64k* q) {
  size_t base = ((size_t)((b * NPART + p) * NN1) + n1) * 16 + typ * 8;
#pragma unroll
  for (int j = 0; j < 8; ++j) q[j] = pq[base + j];
}

__global__ __launch_bounds__(256) void merge_parts_kernel(const u64k* pq, int* idxb) {
  int g = blockIdx.x * blockDim.x + threadIdx.x;
  if (g >= NB * NN1) return;
  int b = g / NN1, n1 = g - b * NN1;
  for (int typ = 0; typ < 2; ++typ) {
    u64k A[8], B[8];
    loadq_(pq, b, 0, n1, typ, A);
    for (int p = 1; p < NPART; ++p) {
      loadq_(pq, b, p, n1, typ, B);
      merge8q_(A, B);
    }
    size_t ob = (size_t)g * 16 + typ * 8;
#pragma unroll
    for (int j = 0; j < 8; ++j) idxb[ob + j] = (int)(A[j] & 0xffffffffull);
  }
}

// ---------------- K5: fused GRU mapping v3 (block = 4 points, GEMM layers) ----------
// Activations in LDS as [c][row], row = wave*16 + k.  D[row][out] = sum_c A[c][row]*Wt[c*64+out].
__device__ __forceinline__ void gemm64_(const float* Ain, const float* Wt,
                                        int ty, int tx, float acc[4][4]) {
#pragma unroll
  for (int i = 0; i < 4; ++i)
#pragma unroll
    for (int j = 0; j < 4; ++j) acc[i][j] = 0.f;
#pragma unroll 8
  for (int c = 0; c < 64; ++c) {
    float4 a  = *(const float4*)&Ain[c * GPAD + ty * 4];
    float4 wv = *(const float4*)&Wt[c * 64 + tx * 4];
    acc[0][0] += a.x * wv.x; acc[0][1] += a.x * wv.y; acc[0][2] += a.x * wv.z; acc[0][3] += a.x * wv.w;
    acc[1][0] += a.y * wv.x; acc[1][1] += a.y * wv.y; acc[1][2] += a.y * wv.z; acc[1][3] += a.y * wv.w;
    acc[2][0] += a.z * wv.x; acc[2][1] += a.z * wv.y; acc[2][2] += a.z * wv.z; acc[2][3] += a.z * wv.w;
    acc[3][0] += a.w * wv.x; acc[3][1] += a.w * wv.y; acc[3][2] += a.w * wv.z; acc[3][3] += a.w * wv.w;
  }
}

__global__ __launch_bounds__(256, 4) void gru_kernel(
    const int* idxb, const float* x1t, const float* x2t,
    const float* p1r, const float* p1ro, const float* p1z,
    const float* p2r, const float* p2ro, const float* p2z,
    const float* wt,
    const float* br0, const float* br1, const float* br2,
    const float* bz0, const float* bz1, const float* bz2,
    const float* bh0, const float* bh1, const float* bh2,
    float* out) {
  __shared__ __align__(16) float A1[64 * GPAD];   // r-L0 acts, then R3
  __shared__ __align__(16) float A2[64 * GPAD];   // r1-out, z-L0, h-L0
  __shared__ float Vpart[16 * 64];                // first 256 floats reused as Vv
  __shared__ float dxs[64 * 4];
  __shared__ int idxs[64];

  int t = threadIdx.x;
  int w = t >> 6, l = t & 63;
  int ty = t >> 4, tx = t & 15;
  int b = blockIdx.y;
  int n1i = blockIdx.x * 4 + w;
  int rowbase = b * NN1 + n1i;

  if (l < 16) {
    int gi = idxb[(size_t)rowbase * 16 + l];
    idxs[w * 16 + l] = gi;
    float4 x1v = ((const float4*)x1t)[rowbase];
    float4 x2v = ((const float4*)x2t)[b * NN2 + gi];
    dxs[(w * 16 + l) * 4 + 0] = x2v.x - x1v.x;
    dxs[(w * 16 + l) * 4 + 1] = x2v.y - x1v.y;
    dxs[(w * 16 + l) * 4 + 2] = x2v.z - x1v.z;
    dxs[(w * 16 + l) * 4 + 3] = 0.f;
  }
  float pr  = p1r [(size_t)rowbase * 64 + l];
  float pro = p1ro[(size_t)rowbase * 64 + l];
  float pz  = p1z [(size_t)rowbase * 64 + l];

  const float* Wr0t = wt + 6 * 4096;
  const float* Wr1t = wt + 7 * 4096;
  const float* Wr2t = wt + 8 * 4096;
  const float* Wz0t = wt + 9 * 4096;
  const float* Wz1t = wt + 10 * 4096;
  const float* Wz2t = wt + 11 * 4096;
  const float* Wh0t = wt + 12 * 4096;
  const float* Wh1t = wt + 13 * 4096;
  const float* Wh2t = wt + 14 * 4096;

  __syncthreads();

  // ---- L0 r -> A1[c=l][row] ----
  {
    float w0 = Wr0t[l], w1 = Wr0t[64 + l], w2 = Wr0t[128 + l], b0 = br0[l];
#pragma unroll
    for (int k = 0; k < 16; ++k) {
      int row = w * 16 + k;
      int gi = idxs[row];
      float g = p2r[((size_t)b * NN2 + gi) * 64 + l];
      float4 d = *(const float4*)&dxs[row * 4];
      A1[l * GPAD + row] = leaky_(b0 + pr + g + w0 * d.x + w1 * d.y + w2 * d.z);
    }
  }
  __syncthreads();

  float acc[4][4];

  // ---- r1: A1 x Wr1t -> leaky -> A2 ----
  gemm64_(A1, Wr1t, ty, tx, acc);
  {
    const float* bq = &br1[tx * 4];
#pragma unroll
    for (int j = 0; j < 4; ++j) {
      float bb = bq[j];
#pragma unroll
      for (int i = 0; i < 4; ++i)
        A2[(tx * 4 + j) * GPAD + ty * 4 + i] = leaky_(acc[i][j] + bb);
    }
  }
  __syncthreads();

  // ---- r2: A2 x Wr2t -> sigm -> A1 (= R3) ----
  gemm64_(A2, Wr2t, ty, tx, acc);
  {
    const float* bq = &br2[tx * 4];
#pragma unroll
    for (int j = 0; j < 4; ++j) {
      float bb = bq[j];
#pragma unroll
      for (int i = 0; i < 4; ++i)
        A1[(tx * 4 + j) * GPAD + ty * 4 + i] = sigm_(acc[i][j] + bb);
    }
  }
  __syncthreads();

  // ---- L0 z -> A2 ----
  {
    float w0 = Wz0t[l], w1 = Wz0t[64 + l], w2 = Wz0t[128 + l], b0 = bz0[l];
#pragma unroll
    for (int k = 0; k < 16; ++k) {
      int row = w * 16 + k;
      int gi = idxs[row];
      float g = p2ro[((size_t)b * NN2 + gi) * 64 + l];
      float4 d = *(const float4*)&dxs[row * 4];
      A2[l * GPAD + row] = leaky_(b0 + pz + g + w0 * d.x + w1 * d.y + w2 * d.z);
    }
  }
  __syncthreads();

  // ---- z1: A2 x Wz1t -> leaky -> max over 4 rows -> Vpart ----
  gemm64_(A2, Wz1t, ty, tx, acc);
  {
    const float* bq = &bz1[tx * 4];
#pragma unroll
    for (int j = 0; j < 4; ++j) {
      float bb = bq[j];
      float m = leaky_(acc[0][j] + bb);
      m = fmaxf(m, leaky_(acc[1][j] + bb));
      m = fmaxf(m, leaky_(acc[2][j] + bb));
      m = fmaxf(m, leaky_(acc[3][j] + bb));
      Vpart[ty * 64 + tx * 4 + j] = m;
    }
  }
  __syncthreads();
  float vm;
  {
    float v0 = Vpart[(w * 4 + 0) * 64 + l];
    float v1 = Vpart[(w * 4 + 1) * 64 + l];
    float v2 = Vpart[(w * 4 + 2) * 64 + l];
    float v3 = Vpart[(w * 4 + 3) * 64 + l];
    vm = fmaxf(fmaxf(v0, v1), fmaxf(v2, v3));
  }
  __syncthreads();
  float* Vv = Vpart;
  Vv[w * 64 + l] = vm;
  __syncthreads();
  float z3;
  {
    float a = bz2[l];
#pragma unroll 8
    for (int c = 0; c < 64; ++c) a += Vv[w * 64 + c] * Wz2t[c * 64 + l];
    z3 = sigm_(a);
  }

  // ---- L0 h -> A2 (uses R3 in A1) ----
  {
    float w0 = Wh0t[l], w1 = Wh0t[64 + l], w2 = Wh0t[128 + l], b0 = bh0[l];
#pragma unroll
    for (int k = 0; k < 16; ++k) {
      int row = w * 16 + k;
      int gi = idxs[row];
      float g = p2z[((size_t)b * NN2 + gi) * 64 + l];
      float4 d = *(const float4*)&dxs[row * 4];
      float r3 = A1[l * GPAD + row];
      A2[l * GPAD + row] = leaky_(b0 + r3 * pro + g + w0 * d.x + w1 * d.y + w2 * d.z);
    }
  }
  __syncthreads();

  // ---- h1: A2 x Wh1t -> leaky -> max -> Vpart ----
  gemm64_(A2, Wh1t, ty, tx, acc);
  {
    const float* bq = &bh1[tx * 4];
#pragma unroll
    for (int j = 0; j < 4; ++j) {
      float bb = bq[j];
      float m = leaky_(acc[0][j] + bb);
      m = fmaxf(m, leaky_(acc[1][j] + bb));
      m = fmaxf(m, leaky_(acc[2][j] + bb));
      m = fmaxf(m, leaky_(acc[3][j] + bb));
      Vpart[ty * 64 + tx * 4 + j] = m;
    }
  }
  __syncthreads();
  {
    float v0 = Vpart[(w * 4 + 0) * 64 + l];
    float v1 = Vpart[(w * 4 + 1) * 64 + l];
    float v2 = Vpart[(w * 4 + 2) * 64 + l];
    float v3 = Vpart[(w * 4 + 3) * 64 + l];
    vm = fmaxf(fmaxf(v0, v1), fmaxf(v2, v3));
  }
  __syncthreads();
  Vv[w * 64 + l] = vm;
  __syncthreads();
  float h3;
  {
    float a = bh2[l];
#pragma unroll 8
    for (int c = 0; c < 64; ++c) a += Vv[w * 64 + c] * Wh2t[c * 64 + l];
    h3 = leaky_(a);
  }

  out[((size_t)b * 64 + l) * NN1 + n1i] = (1.0f - z3) * pro + z3 * h3;
}

extern "C" void kernel_launch(void* const* d_in, const int* in_sizes, int n_in,
                              void* d_out, int out_size, void* d_ws, size_t ws_size,
                              hipStream_t stream) {
  (void)in_sizes; (void)n_in; (void)out_size; (void)ws_size;
  const float* xyz1    = (const float*)d_in[0];
  const float* xyz2    = (const float*)d_in[1];
  const float* points1 = (const float*)d_in[2];
  const float* points2 = (const float*)d_in[3];
  const float* knn1    = (const float*)d_in[4];
  const float* knn2    = (const float*)d_in[5];
  const float* Wfr   = (const float*)d_in[6];
  const float* Wfro  = (const float*)d_in[7];
  const float* Wfz   = (const float*)d_in[8];
  const float* Wfr2  = (const float*)d_in[9];
  const float* Wfro2 = (const float*)d_in[10];
  const float* Wfz2  = (const float*)d_in[11];
  const float* Wr0 = (const float*)d_in[12]; const float* br0 = (const float*)d_in[13];
  const float* Wr1 = (const float*)d_in[14]; const float* br1 = (const float*)d_in[15];
  const float* Wr2 = (const float*)d_in[16]; const float* br2 = (const float*)d_in[17];
  const float* Wz0 = (const float*)d_in[18]; const float* bz0 = (const float*)d_in[19];
  const float* Wz1 = (const float*)d_in[20]; const float* bz1 = (const float*)d_in[21];
  const float* Wz2 = (const float*)d_in[22]; const float* bz2 = (const float*)d_in[23];
  const float* Wh0 = (const float*)d_in[24]; const float* bh0 = (const float*)d_in[25];
  const float* Wh1 = (const float*)d_in[26]; const float* bh1 = (const float*)d_in[27];
  const float* Wh2 = (const float*)d_in[28]; const float* bh2 = (const float*)d_in[29];

  float* W = (float*)d_ws;
  size_t o = 0;
  float* f1n = W + o; o += (size_t)NB * NN1 * 64;
  float* f2n = W + o; o += (size_t)NB * NN2 * 64;
  float* x1t = W + o; o += (size_t)NB * NN1 * 4;
  float* x2t = W + o; o += (size_t)NB * NN2 * 4;
  float* p1r = W + o; o += (size_t)NB * NN1 * 64;
  float* p1ro = W + o; o += (size_t)NB * NN1 * 64;
  float* p1z = W + o; o += (size_t)NB * NN1 * 64;
  float* p2r = W + o; o += (size_t)NB * NN2 * 64;
  float* p2ro = W + o; o += (size_t)NB * NN2 * 64;
  float* p2z = W + o; o += (size_t)NB * NN2 * 64;
  float* wt = W + o; o += (size_t)15 * 4096;
  u64k* pq = (u64k*)(W + o); o += (size_t)2 * NB * NPART * NN1 * 16;
  int* idxb = (int*)(W + o); o += (size_t)NB * NN1 * 16;

  float* out = (float*)d_out;

  hipLaunchKernelGGL(prep_w_kernel, dim3(15), dim3(256), 0, stream,
                     Wfr, Wfro, Wfz, Wfr2, Wfro2, Wfz2,
                     Wr0, Wr1, Wr2, Wz0, Wz1, Wz2, Wh0, Wh1, Wh2, wt);
  hipLaunchKernelGGL(prep_side_kernel, dim3(NN1 / 64, NB), dim3(256), 0, stream,
                     knn1, xyz1, f1n, x1t, NN1);
  hipLaunchKernelGGL(prep_side_kernel, dim3(NN2 / 64, NB), dim3(256), 0, stream,
                     knn2, xyz2, f2n, x2t, NN2);
  hipLaunchKernelGGL(fuse_kernel, dim3(NN1 / 4, NB), dim3(256), 0, stream,
                     points1, wt + 0 * 4096, wt + 1 * 4096, wt + 2 * 4096,
                     p1r, p1ro, p1z, NN1);
  hipLaunchKernelGGL(fuse_kernel, dim3(NN2 / 4, NB), dim3(256), 0, stream,
                     points2, wt + 3 * 4096, wt + 4 * 4096, wt + 5 * 4096,
                     p2r, p2ro, p2z, NN2);
  hipLaunchKernelGGL(knn_kernel, dim3(NN1 / 64, NPART, NB), dim3(256), 0, stream,
                     f1n, f2n, x1t, x2t, pq);
  hipLaunchKernelGGL(merge_parts_kernel, dim3((NB * NN1 + 255) / 256), dim3(256), 0, stream,
                     pq, idxb);
  hipLaunchKernelGGL(gru_kernel, dim3(NN1 / 4, NB), dim3(256), 0, stream,
                     idxb, x1t, x2t, p1r, p1ro, p1z, p2r, p2ro, p2z, wt,
                     br0, br1, br2, bz0, bz1, bz2, bh0, bh1, bh2, out);
}